// Round 1
// baseline (1670.408 us; speedup 1.0000x reference)
//
#include <hip/hip_runtime.h>

#define N_NODES 100000
#define N_EDGES 800000
#define FIN 64
#define HID 128
#define NB1 391   // ceil(N_NODES/256)

// ---------------- utility ----------------
__global__ void zero_int_kernel(int* __restrict__ p, int n) {
    int i = blockIdx.x * 256 + threadIdx.x;
    if (i < n) p[i] = 0;
}

// Detect whether edge_index arrived as int32 or int64.
// If int64 (little-endian, ids < 2^31), every odd 32-bit word is 0.
// If int32, odd words are random node ids (nonzero w.p. ~1).
__global__ void detect_kernel(const int* __restrict__ w, int* __restrict__ flag) {
    int i = blockIdx.x * 256 + threadIdx.x;
    if (i < 8192) {
        if (w[2 * i + 1] != 0) atomicOr(flag, 1);
    }
}

// ---------------- CSR build ----------------
__global__ void hist_kernel(const int* __restrict__ w, const int* __restrict__ flag,
                            int* __restrict__ deg) {
    int e = blockIdx.x * 256 + threadIdx.x;
    if (e >= N_EDGES) return;
    int is32 = *flag;
    int d = is32 ? w[N_EDGES + e] : w[2 * (N_EDGES + e)];
    atomicAdd(&deg[d], 1);
}

__global__ void scan1_kernel(const int* __restrict__ deg, int* __restrict__ off,
                             int* __restrict__ bsums) {
    __shared__ int s[256];
    int t = threadIdx.x;
    int i = blockIdx.x * 256 + t;
    int v = (i < N_NODES) ? deg[i] : 0;
    s[t] = v;
    __syncthreads();
    for (int d = 1; d < 256; d <<= 1) {
        int w = (t >= d) ? s[t - d] : 0;
        __syncthreads();
        s[t] += w;
        __syncthreads();
    }
    if (i < N_NODES) off[i] = s[t] - v;       // block-local exclusive
    if (t == 255) bsums[blockIdx.x] = s[255]; // block total
}

__global__ void scan2_kernel(int* __restrict__ bsums) {
    __shared__ int s[512];
    int t = threadIdx.x;
    int v = (t < NB1) ? bsums[t] : 0;
    s[t] = v;
    __syncthreads();
    for (int d = 1; d < 512; d <<= 1) {
        int w = (t >= d) ? s[t - d] : 0;
        __syncthreads();
        s[t] += w;
        __syncthreads();
    }
    if (t < NB1) bsums[t] = s[t] - v; // exclusive scan of block totals
}

__global__ void scan3_kernel(int* __restrict__ off, const int* __restrict__ bsums,
                             int* __restrict__ cursor) {
    int i = blockIdx.x * 256 + threadIdx.x;
    if (i < N_NODES) {
        int v = off[i] + bsums[blockIdx.x];
        off[i] = v;
        cursor[i] = v;
    }
    if (i == 0) off[N_NODES] = N_EDGES;
}

__global__ void scatter_kernel(const int* __restrict__ w, const int* __restrict__ flag,
                               int* __restrict__ cursor, int* __restrict__ srcs) {
    int e = blockIdx.x * 256 + threadIdx.x;
    if (e >= N_EDGES) return;
    int is32 = *flag;
    int s = is32 ? w[e] : w[2 * e];
    int d = is32 ? w[N_EDGES + e] : w[2 * (N_EDGES + e)];
    int p = atomicAdd(&cursor[d], 1);
    srcs[p] = s;
}

// ---------------- aggregation (CSR gather, one wave per node) ----------------
__global__ void agg1_kernel(const float* __restrict__ x, const int* __restrict__ off,
                            const int* __restrict__ srcs, float* __restrict__ agg) {
    int wid = (blockIdx.x * 256 + threadIdx.x) >> 6; // node id
    int lane = threadIdx.x & 63;                     // feature id
    if (wid >= N_NODES) return;
    int b = __builtin_amdgcn_readfirstlane(off[wid]);
    int e = __builtin_amdgcn_readfirstlane(off[wid + 1]);
    float acc = 0.f;
    for (int p = b; p < e; ++p) {
        int s = srcs[p]; // wave-uniform
        acc += x[(size_t)s * FIN + lane];
    }
    agg[(size_t)wid * FIN + lane] = acc;
}

__global__ void agg2_kernel(const float* __restrict__ h, const int* __restrict__ off,
                            const int* __restrict__ srcs, float* __restrict__ agg) {
    int wid = (blockIdx.x * 256 + threadIdx.x) >> 6; // node id
    int lane = threadIdx.x & 63;                     // 2 features per lane
    if (wid >= N_NODES) return;
    int b = __builtin_amdgcn_readfirstlane(off[wid]);
    int e = __builtin_amdgcn_readfirstlane(off[wid + 1]);
    const float2* h2 = (const float2*)h;
    float2 acc = {0.f, 0.f};
    for (int p = b; p < e; ++p) {
        int s = srcs[p];
        float2 v = h2[(size_t)s * 64 + lane];
        acc.x += v.x;
        acc.y += v.y;
    }
    ((float2*)agg)[(size_t)wid * 64 + lane] = acc;
}

// ---------------- layer 1 GEMM: h1 = elu(agg1@W1_rel^T + x@W1_root^T + b1) ----------------
__global__ __launch_bounds__(256) void gemm1_kernel(
    const float* __restrict__ agg, const float* __restrict__ x,
    const float* __restrict__ Wrel, const float* __restrict__ b1,
    const float* __restrict__ Wroot, float* __restrict__ h1) {
    int i = blockIdx.x * 256 + threadIdx.x;
    if (i >= N_NODES) return;
    float ua[FIN], ux[FIN];
    const float4* ap = (const float4*)(agg + (size_t)i * FIN);
    const float4* xp = (const float4*)(x + (size_t)i * FIN);
#pragma unroll
    for (int k = 0; k < FIN / 4; k++) {
        float4 v = ap[k];
        ua[4 * k] = v.x; ua[4 * k + 1] = v.y; ua[4 * k + 2] = v.z; ua[4 * k + 3] = v.w;
        float4 u = xp[k];
        ux[4 * k] = u.x; ux[4 * k + 1] = u.y; ux[4 * k + 2] = u.z; ux[4 * k + 3] = u.w;
    }
    float* out = h1 + (size_t)i * HID;
    for (int j = 0; j < HID; j += 4) { // j uniform -> W reads become s_loads
        float a0 = b1[j + 0], a1 = b1[j + 1], a2 = b1[j + 2], a3 = b1[j + 3];
#pragma unroll
        for (int k = 0; k < FIN; k++) {
            float q = ua[k];
            a0 += q * Wrel[(j + 0) * FIN + k];
            a1 += q * Wrel[(j + 1) * FIN + k];
            a2 += q * Wrel[(j + 2) * FIN + k];
            a3 += q * Wrel[(j + 3) * FIN + k];
            float r = ux[k];
            a0 += r * Wroot[(j + 0) * FIN + k];
            a1 += r * Wroot[(j + 1) * FIN + k];
            a2 += r * Wroot[(j + 2) * FIN + k];
            a3 += r * Wroot[(j + 3) * FIN + k];
        }
        a0 = a0 > 0.f ? a0 : __expf(a0) - 1.f;
        a1 = a1 > 0.f ? a1 : __expf(a1) - 1.f;
        a2 = a2 > 0.f ? a2 : __expf(a2) - 1.f;
        a3 = a3 > 0.f ? a3 : __expf(a3) - 1.f;
        float4 o = {a0, a1, a2, a3};
        *((float4*)(out + j)) = o;
    }
}

// ---------------- layer 2 part A: t2 = agg2@W2_rel^T + b2 ----------------
__global__ __launch_bounds__(256) void gemm2a_kernel(
    const float* __restrict__ agg2, const float* __restrict__ Wrel,
    const float* __restrict__ b2, float* __restrict__ t2) {
    int i = blockIdx.x * 256 + threadIdx.x;
    if (i >= N_NODES) return;
    float u[HID];
    const float4* ap = (const float4*)(agg2 + (size_t)i * HID);
#pragma unroll
    for (int k = 0; k < HID / 4; k++) {
        float4 v = ap[k];
        u[4 * k] = v.x; u[4 * k + 1] = v.y; u[4 * k + 2] = v.z; u[4 * k + 3] = v.w;
    }
    float* out = t2 + (size_t)i * HID;
    for (int j = 0; j < HID; j += 4) {
        float a0 = b2[j + 0], a1 = b2[j + 1], a2 = b2[j + 2], a3 = b2[j + 3];
#pragma unroll
        for (int k = 0; k < HID; k++) {
            float q = u[k];
            a0 += q * Wrel[(j + 0) * HID + k];
            a1 += q * Wrel[(j + 1) * HID + k];
            a2 += q * Wrel[(j + 2) * HID + k];
            a3 += q * Wrel[(j + 3) * HID + k];
        }
        float4 o = {a0, a1, a2, a3};
        *((float4*)(out + j)) = o;
    }
}

// ---- layer 2 part B + fused MLP head: out = fc2(relu(fc1(t2 + h1@W2_root^T))) ----
__global__ __launch_bounds__(256) void gemm2b_kernel(
    const float* __restrict__ h1, const float* __restrict__ Wroot,
    const float* __restrict__ t2, const float* __restrict__ Wfc1,
    const float* __restrict__ bfc1, const float* __restrict__ Wfc2,
    const float* __restrict__ bfc2, float* __restrict__ out) {
    int i = blockIdx.x * 256 + threadIdx.x;
    if (i >= N_NODES) return;
    float u[HID];
    const float4* hp = (const float4*)(h1 + (size_t)i * HID);
#pragma unroll
    for (int k = 0; k < HID / 4; k++) {
        float4 v = hp[k];
        u[4 * k] = v.x; u[4 * k + 1] = v.y; u[4 * k + 2] = v.z; u[4 * k + 3] = v.w;
    }
    float g[20];
#pragma unroll
    for (int m = 0; m < 20; m++) g[m] = 0.f;
    const float4* tp = (const float4*)(t2 + (size_t)i * HID);
    for (int j = 0; j < HID; j += 4) {
        float4 t = tp[j >> 2];
        float a0 = t.x, a1 = t.y, a2 = t.z, a3 = t.w;
#pragma unroll
        for (int k = 0; k < HID; k++) {
            float q = u[k];
            a0 += q * Wroot[(j + 0) * HID + k];
            a1 += q * Wroot[(j + 1) * HID + k];
            a2 += q * Wroot[(j + 2) * HID + k];
            a3 += q * Wroot[(j + 3) * HID + k];
        }
        // stream h2[j..j+3] straight into the fc1 accumulators (h2 never hits memory)
#pragma unroll
        for (int m = 0; m < 20; m++) {
            g[m] += a0 * Wfc1[m * HID + j + 0] + a1 * Wfc1[m * HID + j + 1] +
                    a2 * Wfc1[m * HID + j + 2] + a3 * Wfc1[m * HID + j + 3];
        }
    }
    float o = bfc2[0];
#pragma unroll
    for (int m = 0; m < 20; m++) {
        float gm = g[m] + bfc1[m];
        o += (gm > 0.f ? gm : 0.f) * Wfc2[m];
    }
    out[i] = o;
}

// ---------------- launch ----------------
extern "C" void kernel_launch(void* const* d_in, const int* in_sizes, int n_in,
                              void* d_out, int out_size, void* d_ws, size_t ws_size,
                              hipStream_t stream) {
    const float* x = (const float*)d_in[0];
    const int* ei = (const int*)d_in[1];
    const float* W1rel = (const float*)d_in[2];
    const float* b1 = (const float*)d_in[3];
    const float* W1root = (const float*)d_in[4];
    const float* W2rel = (const float*)d_in[5];
    const float* b2 = (const float*)d_in[6];
    const float* W2root = (const float*)d_in[7];
    const float* Wfc1 = (const float*)d_in[8];
    const float* bfc1 = (const float*)d_in[9];
    const float* Wfc2 = (const float*)d_in[10];
    const float* bfc2 = (const float*)d_in[11];
    float* out = (float*)d_out;

    char* ws = (char*)d_ws;
    size_t o = 0;
    int* deg = (int*)(ws + o);    o += (size_t)N_NODES * 4;        // 400000
    int* off = (int*)(ws + o);    o += (size_t)(N_NODES + 1) * 4 + 12; // 400016
    int* cursor = (int*)(ws + o); o += (size_t)N_NODES * 4;        // 400000
    int* bsums = (int*)(ws + o);  o += 4096;
    int* flag = (int*)(ws + o);   o += 16;
    int* srcs = (int*)(ws + o);   o += (size_t)N_EDGES * 4;        // 3.2 MB
    float* t2 = (float*)(ws + o);                                  // 51.2 MB
    float* agg1 = t2;             // agg1 (25.6 MB) is dead before t2 is written
    o += (size_t)N_NODES * HID * 4;
    float* h1 = (float*)(ws + o); o += (size_t)N_NODES * HID * 4;  // 51.2 MB
    float* agg2 = (float*)(ws + o); o += (size_t)N_NODES * HID * 4;// 51.2 MB

    zero_int_kernel<<<NB1, 256, 0, stream>>>(deg, N_NODES);
    zero_int_kernel<<<1, 256, 0, stream>>>(flag, 1);
    detect_kernel<<<32, 256, 0, stream>>>(ei, flag);
    hist_kernel<<<(N_EDGES + 255) / 256, 256, 0, stream>>>(ei, flag, deg);
    scan1_kernel<<<NB1, 256, 0, stream>>>(deg, off, bsums);
    scan2_kernel<<<1, 512, 0, stream>>>(bsums);
    scan3_kernel<<<NB1, 256, 0, stream>>>(off, bsums, cursor);
    scatter_kernel<<<(N_EDGES + 255) / 256, 256, 0, stream>>>(ei, flag, cursor, srcs);
    agg1_kernel<<<N_NODES / 4, 256, 0, stream>>>(x, off, srcs, agg1);
    gemm1_kernel<<<NB1, 256, 0, stream>>>(agg1, x, W1rel, b1, W1root, h1);
    agg2_kernel<<<N_NODES / 4, 256, 0, stream>>>(h1, off, srcs, agg2);
    gemm2a_kernel<<<NB1, 256, 0, stream>>>(agg2, W2rel, b2, t2);
    gemm2b_kernel<<<NB1, 256, 0, stream>>>(h1, W2root, t2, Wfc1, bfc1, Wfc2, bfc2, out);
}

// Round 2
// 445.631 us; speedup vs baseline: 3.7484x; 3.7484x over previous
//
#include <hip/hip_runtime.h>

#define N_NODES 100000
#define N_EDGES 800000
#define FIN 64
#define HID 128
#define NB1 391   // ceil(N_NODES/256)

typedef unsigned short ushort_t;
typedef __attribute__((ext_vector_type(8))) short short8;   // 8 bf16 = 4 VGPRs (MFMA A/B frag)
typedef __attribute__((ext_vector_type(4))) float fx4;      // MFMA C/D frag
typedef __attribute__((ext_vector_type(4))) unsigned short us4;

__device__ inline ushort_t f2bf(float f) {   // RNE fp32 -> bf16
    unsigned u = __float_as_uint(f);
    u += 0x7fffu + ((u >> 16) & 1u);
    return (ushort_t)(u >> 16);
}
__device__ inline float bf2f(ushort_t h) { return __uint_as_float(((unsigned)h) << 16); }

// ---------------- utility ----------------
__global__ void zero_int_kernel(int* __restrict__ p, int n) {
    int i = blockIdx.x * 256 + threadIdx.x;
    if (i < n) p[i] = 0;
}

// int32 vs int64 edge_index layout probe (int64 little-endian => odd words all 0)
__global__ void detect_kernel(const int* __restrict__ w, int* __restrict__ flag) {
    int i = blockIdx.x * 256 + threadIdx.x;
    if (i < 8192) {
        if (w[2 * i + 1] != 0) atomicOr(flag, 1);
    }
}

// ---------------- CSR build ----------------
__global__ void hist_kernel(const int* __restrict__ w, const int* __restrict__ flag,
                            int* __restrict__ deg) {
    int e = blockIdx.x * 256 + threadIdx.x;
    if (e >= N_EDGES) return;
    int is32 = *flag;
    int d = is32 ? w[N_EDGES + e] : w[2 * (N_EDGES + e)];
    atomicAdd(&deg[d], 1);
}

__global__ void scan1_kernel(const int* __restrict__ deg, int* __restrict__ off,
                             int* __restrict__ bsums) {
    __shared__ int s[256];
    int t = threadIdx.x;
    int i = blockIdx.x * 256 + t;
    int v = (i < N_NODES) ? deg[i] : 0;
    s[t] = v;
    __syncthreads();
    for (int d = 1; d < 256; d <<= 1) {
        int w = (t >= d) ? s[t - d] : 0;
        __syncthreads();
        s[t] += w;
        __syncthreads();
    }
    if (i < N_NODES) off[i] = s[t] - v;
    if (t == 255) bsums[blockIdx.x] = s[255];
}

__global__ void scan2_kernel(int* __restrict__ bsums) {
    __shared__ int s[512];
    int t = threadIdx.x;
    int v = (t < NB1) ? bsums[t] : 0;
    s[t] = v;
    __syncthreads();
    for (int d = 1; d < 512; d <<= 1) {
        int w = (t >= d) ? s[t - d] : 0;
        __syncthreads();
        s[t] += w;
        __syncthreads();
    }
    if (t < NB1) bsums[t] = s[t] - v;
}

__global__ void scan3_kernel(int* __restrict__ off, const int* __restrict__ bsums,
                             int* __restrict__ cursor) {
    int i = blockIdx.x * 256 + threadIdx.x;
    if (i < N_NODES) {
        int v = off[i] + bsums[blockIdx.x];
        off[i] = v;
        cursor[i] = v;
    }
    if (i == 0) off[N_NODES] = N_EDGES;
}

__global__ void scatter_kernel(const int* __restrict__ w, const int* __restrict__ flag,
                               int* __restrict__ cursor, int* __restrict__ srcs) {
    int e = blockIdx.x * 256 + threadIdx.x;
    if (e >= N_EDGES) return;
    int is32 = *flag;
    int s = is32 ? w[e] : w[2 * e];
    int d = is32 ? w[N_EDGES + e] : w[2 * (N_EDGES + e)];
    int p = atomicAdd(&cursor[d], 1);
    srcs[p] = s;
}

// ---------------- dtype conversion ----------------
__global__ void xcvt_kernel(const float* __restrict__ x, ushort_t* __restrict__ xb) {
    int i = blockIdx.x * 256 + threadIdx.x; // quad id
    if (i >= N_NODES * FIN / 4) return;
    float4 v = ((const float4*)x)[i];
    us4 o = {f2bf(v.x), f2bf(v.y), f2bf(v.z), f2bf(v.w)};
    ((us4*)xb)[i] = o;
}

// Wb1[n][k], k<64 -> W1rel, else W1root. Wb2[n][k], k<128 -> W2rel, else W2root.
__global__ void wcvt_kernel(const float* __restrict__ W1rel, const float* __restrict__ W1root,
                            const float* __restrict__ W2rel, const float* __restrict__ W2root,
                            ushort_t* __restrict__ Wb1, ushort_t* __restrict__ Wb2) {
    int i = blockIdx.x * 256 + threadIdx.x;
    if (i < HID * HID) {
        int n = i >> 7, k = i & 127;
        float v = (k < FIN) ? W1rel[n * FIN + k] : W1root[n * FIN + (k - FIN)];
        Wb1[i] = f2bf(v);
    }
    if (i < HID * 2 * HID) {
        int n = i >> 8, k = i & 255;
        float v = (k < HID) ? W2rel[n * HID + k] : W2root[n * HID + (k - HID)];
        Wb2[i] = f2bf(v);
    }
}

// ---------------- aggregation (CSR gather, one wave per node, bf16 in/out, fp32 acc) ----------------
__global__ void agg1_kernel(const ushort_t* __restrict__ xb, const int* __restrict__ off,
                            const int* __restrict__ srcs, ushort_t* __restrict__ aggb) {
    int wid = (blockIdx.x * 256 + threadIdx.x) >> 6; // node
    int lane = threadIdx.x & 63;                     // feature
    if (wid >= N_NODES) return;
    int b = __builtin_amdgcn_readfirstlane(off[wid]);
    int e = __builtin_amdgcn_readfirstlane(off[wid + 1]);
    float acc = 0.f;
    for (int p = b; p < e; ++p) {
        int s = srcs[p]; // wave-uniform
        acc += bf2f(xb[(size_t)s * FIN + lane]);
    }
    aggb[(size_t)wid * FIN + lane] = f2bf(acc);
}

__global__ void agg2_kernel(const ushort_t* __restrict__ h1b, const int* __restrict__ off,
                            const int* __restrict__ srcs, ushort_t* __restrict__ aggb) {
    int wid = (blockIdx.x * 256 + threadIdx.x) >> 6; // node
    int lane = threadIdx.x & 63;                     // 2 features per lane
    if (wid >= N_NODES) return;
    int b = __builtin_amdgcn_readfirstlane(off[wid]);
    int e = __builtin_amdgcn_readfirstlane(off[wid + 1]);
    const unsigned* h2 = (const unsigned*)h1b;
    float ax = 0.f, ay = 0.f;
    for (int p = b; p < e; ++p) {
        int s = srcs[p];
        unsigned v = h2[(size_t)s * 64 + lane];
        ax += __uint_as_float(v << 16);
        ay += __uint_as_float(v & 0xffff0000u);
    }
    unsigned o = (unsigned)f2bf(ax) | ((unsigned)f2bf(ay) << 16);
    ((unsigned*)aggb)[(size_t)wid * 64 + lane] = o;
}

// ---------------- MFMA GEMM layer 1: h1 = elu([agg1,x] @ Wb1^T + b1), bf16 out ----------------
__global__ __launch_bounds__(256) void g1_kernel(
    const ushort_t* __restrict__ aggb, const ushort_t* __restrict__ xb,
    const ushort_t* __restrict__ Wb1, const float* __restrict__ b1,
    ushort_t* __restrict__ h1b) {
    int wave = (blockIdx.x * 256 + threadIdx.x) >> 6;
    int lane = threadIdx.x & 63;
    int nb = wave << 4; // 16 nodes per wave
    if (nb >= N_NODES) return;
    int quad = lane >> 4, mrow = lane & 15;
    int nA = nb + mrow;
    if (nA >= N_NODES) nA = N_NODES - 1; // clamped rows never stored
    fx4 acc[8];
#pragma unroll
    for (int i = 0; i < 8; i++) acc[i] = (fx4){0.f, 0.f, 0.f, 0.f};
#pragma unroll
    for (int t = 0; t < 4; t++) {
        int k0 = t * 32 + quad * 8;
        const short8* ap = (k0 < FIN)
            ? (const short8*)(aggb + (size_t)nA * FIN + k0)
            : (const short8*)(xb + (size_t)nA * FIN + (k0 - FIN));
        short8 a = *ap;
#pragma unroll
        for (int nt = 0; nt < 8; nt++) {
            short8 bq = *(const short8*)(Wb1 + (size_t)(nt * 16 + mrow) * HID + k0);
            acc[nt] = __builtin_amdgcn_mfma_f32_16x16x32_bf16(a, bq, acc[nt], 0, 0, 0);
        }
    }
#pragma unroll
    for (int nt = 0; nt < 8; nt++) {
#pragma unroll
        for (int r = 0; r < 4; r++) {
            int n2 = nb + quad * 4 + r;
            if (n2 < N_NODES) {
                int j = nt * 16 + mrow;
                float v = acc[nt][r] + b1[j];
                v = v > 0.f ? v : __expf(v) - 1.f;
                h1b[(size_t)n2 * HID + j] = f2bf(v);
            }
        }
    }
}

// ---------------- MFMA GEMM layer 2: t2 = [agg2,h1] @ Wb2^T + b2, bf16 out ----------------
__global__ __launch_bounds__(256) void g2_kernel(
    const ushort_t* __restrict__ agg2b, const ushort_t* __restrict__ h1b,
    const ushort_t* __restrict__ Wb2, const float* __restrict__ b2,
    ushort_t* __restrict__ t2b) {
    int wave = (blockIdx.x * 256 + threadIdx.x) >> 6;
    int lane = threadIdx.x & 63;
    int nb = wave << 4;
    if (nb >= N_NODES) return;
    int quad = lane >> 4, mrow = lane & 15;
    int nA = nb + mrow;
    if (nA >= N_NODES) nA = N_NODES - 1;
    fx4 acc[8];
#pragma unroll
    for (int i = 0; i < 8; i++) acc[i] = (fx4){0.f, 0.f, 0.f, 0.f};
#pragma unroll
    for (int t = 0; t < 8; t++) {
        int k0 = t * 32 + quad * 8;
        const short8* ap = (k0 < HID)
            ? (const short8*)(agg2b + (size_t)nA * HID + k0)
            : (const short8*)(h1b + (size_t)nA * HID + (k0 - HID));
        short8 a = *ap;
#pragma unroll
        for (int nt = 0; nt < 8; nt++) {
            short8 bq = *(const short8*)(Wb2 + (size_t)(nt * 16 + mrow) * (2 * HID) + k0);
            acc[nt] = __builtin_amdgcn_mfma_f32_16x16x32_bf16(a, bq, acc[nt], 0, 0, 0);
        }
    }
#pragma unroll
    for (int nt = 0; nt < 8; nt++) {
#pragma unroll
        for (int r = 0; r < 4; r++) {
            int n2 = nb + quad * 4 + r;
            if (n2 < N_NODES) {
                int j = nt * 16 + mrow;
                float v = acc[nt][r] + b2[j];
                t2b[(size_t)n2 * HID + j] = f2bf(v);
            }
        }
    }
}

// ---------------- fused MLP head: out = fc2(relu(fc1(t2))) ----------------
__global__ __launch_bounds__(256) void head_kernel(
    const ushort_t* __restrict__ t2b, const float* __restrict__ Wfc1,
    const float* __restrict__ bfc1, const float* __restrict__ Wfc2,
    const float* __restrict__ bfc2, float* __restrict__ out) {
    int i = blockIdx.x * 256 + threadIdx.x;
    if (i >= N_NODES) return;
    float g[20];
#pragma unroll
    for (int m = 0; m < 20; m++) g[m] = 0.f;
    const uint4* row = (const uint4*)(t2b + (size_t)i * HID);
    for (int c = 0; c < 16; c++) { // 16 chunks of 8 features
        uint4 v = row[c];
        float f0 = __uint_as_float(v.x << 16), f1 = __uint_as_float(v.x & 0xffff0000u);
        float f2 = __uint_as_float(v.y << 16), f3 = __uint_as_float(v.y & 0xffff0000u);
        float f4 = __uint_as_float(v.z << 16), f5 = __uint_as_float(v.z & 0xffff0000u);
        float f6 = __uint_as_float(v.w << 16), f7 = __uint_as_float(v.w & 0xffff0000u);
        int j = c * 8;
#pragma unroll
        for (int m = 0; m < 20; m++) {
            const float* w = Wfc1 + m * HID + j; // j,m uniform -> s_loads
            g[m] += f0 * w[0] + f1 * w[1] + f2 * w[2] + f3 * w[3] +
                    f4 * w[4] + f5 * w[5] + f6 * w[6] + f7 * w[7];
        }
    }
    float o = bfc2[0];
#pragma unroll
    for (int m = 0; m < 20; m++) {
        float gm = g[m] + bfc1[m];
        o += (gm > 0.f ? gm : 0.f) * Wfc2[m];
    }
    out[i] = o;
}

// ---------------- launch ----------------
extern "C" void kernel_launch(void* const* d_in, const int* in_sizes, int n_in,
                              void* d_out, int out_size, void* d_ws, size_t ws_size,
                              hipStream_t stream) {
    const float* x = (const float*)d_in[0];
    const int* ei = (const int*)d_in[1];
    const float* W1rel = (const float*)d_in[2];
    const float* b1 = (const float*)d_in[3];
    const float* W1root = (const float*)d_in[4];
    const float* W2rel = (const float*)d_in[5];
    const float* b2 = (const float*)d_in[6];
    const float* W2root = (const float*)d_in[7];
    const float* Wfc1 = (const float*)d_in[8];
    const float* bfc1 = (const float*)d_in[9];
    const float* Wfc2 = (const float*)d_in[10];
    const float* bfc2 = (const float*)d_in[11];
    float* out = (float*)d_out;

    char* ws = (char*)d_ws;
    size_t o = 0;
    int* deg = (int*)(ws + o);       o += (size_t)N_NODES * 4;          // 400000
    int* off = (int*)(ws + o);       o += (size_t)(N_NODES + 1) * 4 + 12;
    int* cursor = (int*)(ws + o);    o += (size_t)N_NODES * 4;
    int* bsums = (int*)(ws + o);     o += 4096;
    int* flag = (int*)(ws + o);      o += 16;
    int* srcs = (int*)(ws + o);      o += (size_t)N_EDGES * 4;          // 3.2 MB
    ushort_t* xb = (ushort_t*)(ws + o);    o += (size_t)N_NODES * FIN * 2;  // 12.8 MB
    ushort_t* agg1b = (ushort_t*)(ws + o); o += (size_t)N_NODES * FIN * 2;  // 12.8 MB
    ushort_t* h1b = (ushort_t*)(ws + o);   o += (size_t)N_NODES * HID * 2;  // 25.6 MB
    ushort_t* agg2b = (ushort_t*)(ws + o); o += (size_t)N_NODES * HID * 2;  // 25.6 MB
    ushort_t* t2b = (ushort_t*)(ws + o);   o += (size_t)N_NODES * HID * 2;  // 25.6 MB
    ushort_t* Wb1 = (ushort_t*)(ws + o);   o += (size_t)HID * HID * 2;      // 32 KB
    ushort_t* Wb2 = (ushort_t*)(ws + o);   o += (size_t)HID * 2 * HID * 2;  // 64 KB

    const int GW = (N_NODES + 63) / 64; // blocks for MFMA gemms (4 waves x 16 nodes)

    zero_int_kernel<<<NB1, 256, 0, stream>>>(deg, N_NODES);
    zero_int_kernel<<<1, 256, 0, stream>>>(flag, 1);
    detect_kernel<<<32, 256, 0, stream>>>(ei, flag);
    hist_kernel<<<(N_EDGES + 255) / 256, 256, 0, stream>>>(ei, flag, deg);
    scan1_kernel<<<NB1, 256, 0, stream>>>(deg, off, bsums);
    scan2_kernel<<<1, 512, 0, stream>>>(bsums);
    scan3_kernel<<<NB1, 256, 0, stream>>>(off, bsums, cursor);
    scatter_kernel<<<(N_EDGES + 255) / 256, 256, 0, stream>>>(ei, flag, cursor, srcs);
    xcvt_kernel<<<(N_NODES * FIN / 4 + 255) / 256, 256, 0, stream>>>(x, xb);
    wcvt_kernel<<<(HID * 2 * HID + 255) / 256, 256, 0, stream>>>(W1rel, W1root, W2rel, W2root, Wb1, Wb2);
    agg1_kernel<<<N_NODES / 4, 256, 0, stream>>>(xb, off, srcs, agg1b);
    g1_kernel<<<GW, 256, 0, stream>>>(agg1b, xb, Wb1, b1, h1b);
    agg2_kernel<<<N_NODES / 4, 256, 0, stream>>>(h1b, off, srcs, agg2b);
    g2_kernel<<<GW, 256, 0, stream>>>(agg2b, h1b, Wb2, b2, t2b);
    head_kernel<<<NB1, 256, 0, stream>>>(t2b, Wfc1, bfc1, Wfc2, bfc2, out);
}

// Round 3
// 370.652 us; speedup vs baseline: 4.5067x; 1.2023x over previous
//
#include <hip/hip_runtime.h>

#define N_NODES 100000
#define N_EDGES 800000
#define FIN 64
#define HID 128
#define NB1 391   // ceil(N_NODES/256)

typedef unsigned short ushort_t;
typedef __attribute__((ext_vector_type(8))) short short8;   // 8 bf16 = 4 VGPRs (MFMA A/B frag)
typedef __attribute__((ext_vector_type(16))) float fx16;    // 32x32 MFMA C/D frag
typedef __attribute__((ext_vector_type(4))) unsigned short us4;

__device__ inline ushort_t f2bf(float f) {   // RNE fp32 -> bf16
    unsigned u = __float_as_uint(f);
    u += 0x7fffu + ((u >> 16) & 1u);
    return (ushort_t)(u >> 16);
}
__device__ inline float bf2f(ushort_t h) { return __uint_as_float(((unsigned)h) << 16); }

// ---------------- utility ----------------
__global__ void zero_int_kernel(int* __restrict__ p, int n) {
    int i = blockIdx.x * 256 + threadIdx.x;
    if (i < n) p[i] = 0;
}

// int32 vs int64 edge_index layout probe (int64 little-endian => odd words all 0)
__global__ void detect_kernel(const int* __restrict__ w, int* __restrict__ flag) {
    int i = blockIdx.x * 256 + threadIdx.x;
    if (i < 8192) {
        if (w[2 * i + 1] != 0) atomicOr(flag, 1);
    }
}

// ---------------- CSR build ----------------
__global__ void hist_kernel(const int* __restrict__ w, const int* __restrict__ flag,
                            int* __restrict__ deg) {
    int e = blockIdx.x * 256 + threadIdx.x;
    if (e >= N_EDGES) return;
    int is32 = *flag;
    int d = is32 ? w[N_EDGES + e] : w[2 * (N_EDGES + e)];
    atomicAdd(&deg[d], 1);
}

__global__ void scan1_kernel(const int* __restrict__ deg, int* __restrict__ off,
                             int* __restrict__ bsums) {
    __shared__ int s[256];
    int t = threadIdx.x;
    int i = blockIdx.x * 256 + t;
    int v = (i < N_NODES) ? deg[i] : 0;
    s[t] = v;
    __syncthreads();
    for (int d = 1; d < 256; d <<= 1) {
        int w = (t >= d) ? s[t - d] : 0;
        __syncthreads();
        s[t] += w;
        __syncthreads();
    }
    if (i < N_NODES) off[i] = s[t] - v;
    if (t == 255) bsums[blockIdx.x] = s[255];
}

__global__ void scan2_kernel(int* __restrict__ bsums) {
    __shared__ int s[512];
    int t = threadIdx.x;
    int v = (t < NB1) ? bsums[t] : 0;
    s[t] = v;
    __syncthreads();
    for (int d = 1; d < 512; d <<= 1) {
        int w = (t >= d) ? s[t - d] : 0;
        __syncthreads();
        s[t] += w;
        __syncthreads();
    }
    if (t < NB1) bsums[t] = s[t] - v;
}

__global__ void scan3_kernel(int* __restrict__ off, const int* __restrict__ bsums,
                             int* __restrict__ cursor) {
    int i = blockIdx.x * 256 + threadIdx.x;
    if (i < N_NODES) {
        int v = off[i] + bsums[blockIdx.x];
        off[i] = v;
        cursor[i] = v;
    }
    if (i == 0) off[N_NODES] = N_EDGES;
}

__global__ void scatter_kernel(const int* __restrict__ w, const int* __restrict__ flag,
                               int* __restrict__ cursor, int* __restrict__ srcs) {
    int e = blockIdx.x * 256 + threadIdx.x;
    if (e >= N_EDGES) return;
    int is32 = *flag;
    int s = is32 ? w[e] : w[2 * e];
    int d = is32 ? w[N_EDGES + e] : w[2 * (N_EDGES + e)];
    int p = atomicAdd(&cursor[d], 1);
    srcs[p] = s;
}

// ---------------- dtype conversion ----------------
__global__ void xcvt_kernel(const float* __restrict__ x, ushort_t* __restrict__ xb) {
    int i = blockIdx.x * 256 + threadIdx.x; // quad id
    if (i >= N_NODES * FIN / 4) return;
    float4 v = ((const float4*)x)[i];
    us4 o = {f2bf(v.x), f2bf(v.y), f2bf(v.z), f2bf(v.w)};
    ((us4*)xb)[i] = o;
}

// Wb1[n][k], k<64 -> W1rel, else W1root. Wb2[n][k], k<128 -> W2rel, else W2root.
__global__ void wcvt_kernel(const float* __restrict__ W1rel, const float* __restrict__ W1root,
                            const float* __restrict__ W2rel, const float* __restrict__ W2root,
                            ushort_t* __restrict__ Wb1, ushort_t* __restrict__ Wb2) {
    int i = blockIdx.x * 256 + threadIdx.x;
    if (i < HID * HID) {
        int n = i >> 7, k = i & 127;
        float v = (k < FIN) ? W1rel[n * FIN + k] : W1root[n * FIN + (k - FIN)];
        Wb1[i] = f2bf(v);
    }
    if (i < HID * 2 * HID) {
        int n = i >> 8, k = i & 255;
        float v = (k < HID) ? W2rel[n * HID + k] : W2root[n * HID + (k - HID)];
        Wb2[i] = f2bf(v);
    }
}

// ------- aggregation (CSR gather, one wave per node, x4 unrolled for MLP) -------
__global__ void agg1_kernel(const ushort_t* __restrict__ xb, const int* __restrict__ off,
                            const int* __restrict__ srcs, ushort_t* __restrict__ aggb) {
    int wid = (blockIdx.x * 256 + threadIdx.x) >> 6; // node
    int lane = threadIdx.x & 63;                     // feature
    if (wid >= N_NODES) return;
    int b = __builtin_amdgcn_readfirstlane(off[wid]);
    int e = __builtin_amdgcn_readfirstlane(off[wid + 1]);
    float a0 = 0.f, a1 = 0.f, a2 = 0.f, a3 = 0.f;
    int p = b;
    for (; p + 4 <= e; p += 4) {
        int s0 = srcs[p], s1 = srcs[p + 1], s2 = srcs[p + 2], s3 = srcs[p + 3];
        a0 += bf2f(xb[(size_t)s0 * FIN + lane]);
        a1 += bf2f(xb[(size_t)s1 * FIN + lane]);
        a2 += bf2f(xb[(size_t)s2 * FIN + lane]);
        a3 += bf2f(xb[(size_t)s3 * FIN + lane]);
    }
    for (; p < e; ++p) {
        int s = srcs[p];
        a0 += bf2f(xb[(size_t)s * FIN + lane]);
    }
    aggb[(size_t)wid * FIN + lane] = f2bf((a0 + a1) + (a2 + a3));
}

__global__ void agg2_kernel(const ushort_t* __restrict__ h1b, const int* __restrict__ off,
                            const int* __restrict__ srcs, ushort_t* __restrict__ aggb) {
    int wid = (blockIdx.x * 256 + threadIdx.x) >> 6; // node
    int lane = threadIdx.x & 63;                     // 2 features per lane
    if (wid >= N_NODES) return;
    int b = __builtin_amdgcn_readfirstlane(off[wid]);
    int e = __builtin_amdgcn_readfirstlane(off[wid + 1]);
    const unsigned* h2 = (const unsigned*)h1b;
    float x0 = 0.f, y0 = 0.f, x1 = 0.f, y1 = 0.f;
    float x2 = 0.f, y2 = 0.f, x3 = 0.f, y3 = 0.f;
    int p = b;
    for (; p + 4 <= e; p += 4) {
        int s0 = srcs[p], s1 = srcs[p + 1], s2 = srcs[p + 2], s3 = srcs[p + 3];
        unsigned v0 = h2[(size_t)s0 * 64 + lane];
        unsigned v1 = h2[(size_t)s1 * 64 + lane];
        unsigned v2 = h2[(size_t)s2 * 64 + lane];
        unsigned v3 = h2[(size_t)s3 * 64 + lane];
        x0 += __uint_as_float(v0 << 16); y0 += __uint_as_float(v0 & 0xffff0000u);
        x1 += __uint_as_float(v1 << 16); y1 += __uint_as_float(v1 & 0xffff0000u);
        x2 += __uint_as_float(v2 << 16); y2 += __uint_as_float(v2 & 0xffff0000u);
        x3 += __uint_as_float(v3 << 16); y3 += __uint_as_float(v3 & 0xffff0000u);
    }
    for (; p < e; ++p) {
        int s = srcs[p];
        unsigned v = h2[(size_t)s * 64 + lane];
        x0 += __uint_as_float(v << 16); y0 += __uint_as_float(v & 0xffff0000u);
    }
    float ax = (x0 + x1) + (x2 + x3);
    float ay = (y0 + y1) + (y2 + y3);
    unsigned o = (unsigned)f2bf(ax) | ((unsigned)f2bf(ay) << 16);
    ((unsigned*)aggb)[(size_t)wid * 64 + lane] = o;
}

// ------- MFMA GEMM layer 1: h1 = elu([agg1,x] @ Wb1^T + b1), 32x32x16, M=32/wave -------
__global__ __launch_bounds__(256) void g1_kernel(
    const ushort_t* __restrict__ aggb, const ushort_t* __restrict__ xb,
    const ushort_t* __restrict__ Wb1, const float* __restrict__ b1,
    ushort_t* __restrict__ h1b) {
    int wave = (blockIdx.x * 256 + threadIdx.x) >> 6;
    int lane = threadIdx.x & 63;
    int nb = wave << 5; // 32 nodes per wave
    if (nb >= N_NODES) return;
    int half = lane >> 5, col = lane & 31;
    int kh = half * 8;
    int nA = nb + col;
    if (nA >= N_NODES) nA = N_NODES - 1; // clamped rows never stored
    fx16 acc[4];
#pragma unroll
    for (int jt = 0; jt < 4; jt++)
#pragma unroll
        for (int r = 0; r < 16; r++) acc[jt][r] = 0.f;
#pragma unroll
    for (int s = 0; s < 8; s++) { // K = 128, 16 per step
        int k0 = s * 16 + kh;
        const short8* ap = (k0 < FIN)
            ? (const short8*)(aggb + (size_t)nA * FIN + k0)
            : (const short8*)(xb + (size_t)nA * FIN + (k0 - FIN));
        short8 a = *ap;
#pragma unroll
        for (int jt = 0; jt < 4; jt++) {
            short8 bq = *(const short8*)(Wb1 + (size_t)(jt * 32 + col) * HID + k0);
            acc[jt] = __builtin_amdgcn_mfma_f32_32x32x16_bf16(a, bq, acc[jt], 0, 0, 0);
        }
    }
#pragma unroll
    for (int jt = 0; jt < 4; jt++) {
        int j = jt * 32 + col;
        float bias = b1[j];
#pragma unroll
        for (int r = 0; r < 16; r++) {
            int node = nb + (r & 3) + 8 * (r >> 2) + 4 * half;
            if (node < N_NODES) {
                float v = acc[jt][r] + bias;
                v = v > 0.f ? v : __expf(v) - 1.f;
                h1b[(size_t)node * HID + j] = f2bf(v);
            }
        }
    }
}

// ------- MFMA GEMM layer 2: t2 = [agg2,h1] @ Wb2^T + b2, 32x32x16, M=32/wave -------
__global__ __launch_bounds__(256) void g2_kernel(
    const ushort_t* __restrict__ agg2b, const ushort_t* __restrict__ h1b,
    const ushort_t* __restrict__ Wb2, const float* __restrict__ b2,
    ushort_t* __restrict__ t2b) {
    int wave = (blockIdx.x * 256 + threadIdx.x) >> 6;
    int lane = threadIdx.x & 63;
    int nb = wave << 5;
    if (nb >= N_NODES) return;
    int half = lane >> 5, col = lane & 31;
    int kh = half * 8;
    int nA = nb + col;
    if (nA >= N_NODES) nA = N_NODES - 1;
    fx16 acc[4];
#pragma unroll
    for (int jt = 0; jt < 4; jt++)
#pragma unroll
        for (int r = 0; r < 16; r++) acc[jt][r] = 0.f;
#pragma unroll
    for (int s = 0; s < 16; s++) { // K = 256, 16 per step
        int k0 = s * 16 + kh;
        const short8* ap = (k0 < HID)
            ? (const short8*)(agg2b + (size_t)nA * HID + k0)
            : (const short8*)(h1b + (size_t)nA * HID + (k0 - HID));
        short8 a = *ap;
#pragma unroll
        for (int jt = 0; jt < 4; jt++) {
            short8 bq = *(const short8*)(Wb2 + (size_t)(jt * 32 + col) * (2 * HID) + k0);
            acc[jt] = __builtin_amdgcn_mfma_f32_32x32x16_bf16(a, bq, acc[jt], 0, 0, 0);
        }
    }
#pragma unroll
    for (int jt = 0; jt < 4; jt++) {
        int j = jt * 32 + col;
        float bias = b2[j];
#pragma unroll
        for (int r = 0; r < 16; r++) {
            int node = nb + (r & 3) + 8 * (r >> 2) + 4 * half;
            if (node < N_NODES) {
                float v = acc[jt][r] + bias;
                t2b[(size_t)node * HID + j] = f2bf(v);
            }
        }
    }
}

// ---------------- fused MLP head: out = fc2(relu(fc1(t2))) ----------------
__global__ __launch_bounds__(256) void head_kernel(
    const ushort_t* __restrict__ t2b, const float* __restrict__ Wfc1,
    const float* __restrict__ bfc1, const float* __restrict__ Wfc2,
    const float* __restrict__ bfc2, float* __restrict__ out) {
    int i = blockIdx.x * 256 + threadIdx.x;
    if (i >= N_NODES) return;
    float g[20];
#pragma unroll
    for (int m = 0; m < 20; m++) g[m] = 0.f;
    const uint4* row = (const uint4*)(t2b + (size_t)i * HID);
    for (int c = 0; c < 16; c++) { // 16 chunks of 8 features
        uint4 v = row[c];
        float f0 = __uint_as_float(v.x << 16), f1 = __uint_as_float(v.x & 0xffff0000u);
        float f2 = __uint_as_float(v.y << 16), f3 = __uint_as_float(v.y & 0xffff0000u);
        float f4 = __uint_as_float(v.z << 16), f5 = __uint_as_float(v.z & 0xffff0000u);
        float f6 = __uint_as_float(v.w << 16), f7 = __uint_as_float(v.w & 0xffff0000u);
        int j = c * 8;
#pragma unroll
        for (int m = 0; m < 20; m++) {
            const float* w = Wfc1 + m * HID + j; // j,m uniform -> s_loads
            g[m] += f0 * w[0] + f1 * w[1] + f2 * w[2] + f3 * w[3] +
                    f4 * w[4] + f5 * w[5] + f6 * w[6] + f7 * w[7];
        }
    }
    float o = bfc2[0];
#pragma unroll
    for (int m = 0; m < 20; m++) {
        float gm = g[m] + bfc1[m];
        o += (gm > 0.f ? gm : 0.f) * Wfc2[m];
    }
    out[i] = o;
}

// ---------------- launch ----------------
extern "C" void kernel_launch(void* const* d_in, const int* in_sizes, int n_in,
                              void* d_out, int out_size, void* d_ws, size_t ws_size,
                              hipStream_t stream) {
    const float* x = (const float*)d_in[0];
    const int* ei = (const int*)d_in[1];
    const float* W1rel = (const float*)d_in[2];
    const float* b1 = (const float*)d_in[3];
    const float* W1root = (const float*)d_in[4];
    const float* W2rel = (const float*)d_in[5];
    const float* b2 = (const float*)d_in[6];
    const float* W2root = (const float*)d_in[7];
    const float* Wfc1 = (const float*)d_in[8];
    const float* bfc1 = (const float*)d_in[9];
    const float* Wfc2 = (const float*)d_in[10];
    const float* bfc2 = (const float*)d_in[11];
    float* out = (float*)d_out;

    char* ws = (char*)d_ws;
    size_t o = 0;
    int* deg = (int*)(ws + o);       o += (size_t)N_NODES * 4;
    int* off = (int*)(ws + o);       o += (size_t)(N_NODES + 1) * 4 + 12;
    int* cursor = (int*)(ws + o);    o += (size_t)N_NODES * 4;
    int* bsums = (int*)(ws + o);     o += 4096;
    int* flag = (int*)(ws + o);      o += 16;
    int* srcs = (int*)(ws + o);      o += (size_t)N_EDGES * 4;          // 3.2 MB
    ushort_t* xb = (ushort_t*)(ws + o);    o += (size_t)N_NODES * FIN * 2;  // 12.8 MB
    ushort_t* agg1b = (ushort_t*)(ws + o); o += (size_t)N_NODES * FIN * 2;  // 12.8 MB
    ushort_t* h1b = (ushort_t*)(ws + o);   o += (size_t)N_NODES * HID * 2;  // 25.6 MB
    ushort_t* agg2b = (ushort_t*)(ws + o); o += (size_t)N_NODES * HID * 2;  // 25.6 MB
    ushort_t* t2b = (ushort_t*)(ws + o);   o += (size_t)N_NODES * HID * 2;  // 25.6 MB
    ushort_t* Wb1 = (ushort_t*)(ws + o);   o += (size_t)HID * HID * 2;      // 32 KB
    ushort_t* Wb2 = (ushort_t*)(ws + o);   o += (size_t)HID * 2 * HID * 2;  // 64 KB

    const int GW = (N_NODES + 127) / 128; // 782 blocks: 4 waves x 32 nodes per block

    zero_int_kernel<<<NB1, 256, 0, stream>>>(deg, N_NODES);
    zero_int_kernel<<<1, 256, 0, stream>>>(flag, 1);
    detect_kernel<<<32, 256, 0, stream>>>(ei, flag);
    hist_kernel<<<(N_EDGES + 255) / 256, 256, 0, stream>>>(ei, flag, deg);
    scan1_kernel<<<NB1, 256, 0, stream>>>(deg, off, bsums);
    scan2_kernel<<<1, 512, 0, stream>>>(bsums);
    scan3_kernel<<<NB1, 256, 0, stream>>>(off, bsums, cursor);
    scatter_kernel<<<(N_EDGES + 255) / 256, 256, 0, stream>>>(ei, flag, cursor, srcs);
    xcvt_kernel<<<(N_NODES * FIN / 4 + 255) / 256, 256, 0, stream>>>(x, xb);
    wcvt_kernel<<<(HID * 2 * HID + 255) / 256, 256, 0, stream>>>(W1rel, W1root, W2rel, W2root, Wb1, Wb2);
    agg1_kernel<<<N_NODES / 4, 256, 0, stream>>>(xb, off, srcs, agg1b);
    g1_kernel<<<GW, 256, 0, stream>>>(agg1b, xb, Wb1, b1, h1b);
    agg2_kernel<<<N_NODES / 4, 256, 0, stream>>>(h1b, off, srcs, agg2b);
    g2_kernel<<<GW, 256, 0, stream>>>(agg2b, h1b, Wb2, b2, t2b);
    head_kernel<<<NB1, 256, 0, stream>>>(t2b, Wfc1, bfc1, Wfc2, bfc2, out);
}

// Round 4
// 330.104 us; speedup vs baseline: 5.0602x; 1.1228x over previous
//
#include <hip/hip_runtime.h>

#define N_NODES 100000
#define N_EDGES 800000
#define FIN 64
#define HID 128
#define NB1 391   // ceil(N_NODES/256)

typedef unsigned short ushort_t;
typedef __attribute__((ext_vector_type(8))) short short8;   // 8 bf16 = 4 VGPRs (MFMA A/B frag)
typedef __attribute__((ext_vector_type(16))) float fx16;    // 32x32 MFMA C/D frag
typedef __attribute__((ext_vector_type(4))) unsigned short us4;

__device__ inline ushort_t f2bf(float f) {   // RNE fp32 -> bf16
    unsigned u = __float_as_uint(f);
    u += 0x7fffu + ((u >> 16) & 1u);
    return (ushort_t)(u >> 16);
}
__device__ inline float bf2f(ushort_t h) { return __uint_as_float(((unsigned)h) << 16); }

// ---------------- utility ----------------
__global__ void zero_int_kernel(int* __restrict__ p, int n) {
    int i = blockIdx.x * 256 + threadIdx.x;
    if (i < n) p[i] = 0;
}

// int32 vs int64 edge_index layout probe (int64 little-endian => odd words all 0)
__global__ void detect_kernel(const int* __restrict__ w, int* __restrict__ flag) {
    int i = blockIdx.x * 256 + threadIdx.x;
    if (i < 8192) {
        if (w[2 * i + 1] != 0) atomicOr(flag, 1);
    }
}

// ---------------- CSR build ----------------
// hist: degree count AND per-edge rank (the atomic's return value — free rank assignment,
// rank[] write is coalesced). This removes the atomic from the scatter pass entirely.
__global__ void hist_kernel(const int* __restrict__ w, const int* __restrict__ flag,
                            int* __restrict__ deg, int* __restrict__ rank) {
    int e = blockIdx.x * 256 + threadIdx.x;
    if (e >= N_EDGES) return;
    int is32 = *flag;
    int d = is32 ? w[N_EDGES + e] : w[2 * (N_EDGES + e)];
    rank[e] = atomicAdd(&deg[d], 1);
}

__global__ void scan1_kernel(const int* __restrict__ deg, int* __restrict__ off,
                             int* __restrict__ bsums) {
    __shared__ int s[256];
    int t = threadIdx.x;
    int i = blockIdx.x * 256 + t;
    int v = (i < N_NODES) ? deg[i] : 0;
    s[t] = v;
    __syncthreads();
    for (int d = 1; d < 256; d <<= 1) {
        int w = (t >= d) ? s[t - d] : 0;
        __syncthreads();
        s[t] += w;
        __syncthreads();
    }
    if (i < N_NODES) off[i] = s[t] - v;
    if (t == 255) bsums[blockIdx.x] = s[255];
}

__global__ void scan2_kernel(int* __restrict__ bsums) {
    __shared__ int s[512];
    int t = threadIdx.x;
    int v = (t < NB1) ? bsums[t] : 0;
    s[t] = v;
    __syncthreads();
    for (int d = 1; d < 512; d <<= 1) {
        int w = (t >= d) ? s[t - d] : 0;
        __syncthreads();
        s[t] += w;
        __syncthreads();
    }
    if (t < NB1) bsums[t] = s[t] - v;
}

__global__ void scan3_kernel(int* __restrict__ off, const int* __restrict__ bsums) {
    int i = blockIdx.x * 256 + threadIdx.x;
    if (i < N_NODES) off[i] = off[i] + bsums[blockIdx.x];
    if (i == 0) off[N_NODES] = N_EDGES;
}

// scatter: atomic-free. p = off[dst] + rank[e]. off read is L2-cached (400 KB),
// rank read coalesced; only the 4B srcs store is random.
__global__ void scatter_kernel(const int* __restrict__ w, const int* __restrict__ flag,
                               const int* __restrict__ off, const int* __restrict__ rank,
                               int* __restrict__ srcs) {
    int e = blockIdx.x * 256 + threadIdx.x;
    if (e >= N_EDGES) return;
    int is32 = *flag;
    int s = is32 ? w[e] : w[2 * e];
    int d = is32 ? w[N_EDGES + e] : w[2 * (N_EDGES + e)];
    srcs[off[d] + rank[e]] = s;
}

// ---------------- dtype conversion ----------------
__global__ void xcvt_kernel(const float* __restrict__ x, ushort_t* __restrict__ xb) {
    int i = blockIdx.x * 256 + threadIdx.x; // quad id
    if (i >= N_NODES * FIN / 4) return;
    float4 v = ((const float4*)x)[i];
    us4 o = {f2bf(v.x), f2bf(v.y), f2bf(v.z), f2bf(v.w)};
    ((us4*)xb)[i] = o;
}

// Wb1[n][k], k<64 -> W1rel, else W1root. Wb2[n][k], k<128 -> W2rel, else W2root.
__global__ void wcvt_kernel(const float* __restrict__ W1rel, const float* __restrict__ W1root,
                            const float* __restrict__ W2rel, const float* __restrict__ W2root,
                            ushort_t* __restrict__ Wb1, ushort_t* __restrict__ Wb2) {
    int i = blockIdx.x * 256 + threadIdx.x;
    if (i < HID * HID) {
        int n = i >> 7, k = i & 127;
        float v = (k < FIN) ? W1rel[n * FIN + k] : W1root[n * FIN + (k - FIN)];
        Wb1[i] = f2bf(v);
    }
    if (i < HID * 2 * HID) {
        int n = i >> 8, k = i & 255;
        float v = (k < HID) ? W2rel[n * HID + k] : W2root[n * HID + (k - HID)];
        Wb2[i] = f2bf(v);
    }
}

// ------- aggregation (CSR gather, one wave per node, x4 unrolled for MLP) -------
__global__ void agg1_kernel(const ushort_t* __restrict__ xb, const int* __restrict__ off,
                            const int* __restrict__ srcs, ushort_t* __restrict__ aggb) {
    int wid = (blockIdx.x * 256 + threadIdx.x) >> 6; // node
    int lane = threadIdx.x & 63;                     // feature
    if (wid >= N_NODES) return;
    int b = __builtin_amdgcn_readfirstlane(off[wid]);
    int e = __builtin_amdgcn_readfirstlane(off[wid + 1]);
    float a0 = 0.f, a1 = 0.f, a2 = 0.f, a3 = 0.f;
    int p = b;
    for (; p + 4 <= e; p += 4) {
        int s0 = srcs[p], s1 = srcs[p + 1], s2 = srcs[p + 2], s3 = srcs[p + 3];
        a0 += bf2f(xb[(size_t)s0 * FIN + lane]);
        a1 += bf2f(xb[(size_t)s1 * FIN + lane]);
        a2 += bf2f(xb[(size_t)s2 * FIN + lane]);
        a3 += bf2f(xb[(size_t)s3 * FIN + lane]);
    }
    for (; p < e; ++p) {
        int s = srcs[p];
        a0 += bf2f(xb[(size_t)s * FIN + lane]);
    }
    aggb[(size_t)wid * FIN + lane] = f2bf((a0 + a1) + (a2 + a3));
}

__global__ void agg2_kernel(const ushort_t* __restrict__ h1b, const int* __restrict__ off,
                            const int* __restrict__ srcs, ushort_t* __restrict__ aggb) {
    int wid = (blockIdx.x * 256 + threadIdx.x) >> 6; // node
    int lane = threadIdx.x & 63;                     // 2 features per lane
    if (wid >= N_NODES) return;
    int b = __builtin_amdgcn_readfirstlane(off[wid]);
    int e = __builtin_amdgcn_readfirstlane(off[wid + 1]);
    const unsigned* h2 = (const unsigned*)h1b;
    float x0 = 0.f, y0 = 0.f, x1 = 0.f, y1 = 0.f;
    float x2 = 0.f, y2 = 0.f, x3 = 0.f, y3 = 0.f;
    int p = b;
    for (; p + 4 <= e; p += 4) {
        int s0 = srcs[p], s1 = srcs[p + 1], s2 = srcs[p + 2], s3 = srcs[p + 3];
        unsigned v0 = h2[(size_t)s0 * 64 + lane];
        unsigned v1 = h2[(size_t)s1 * 64 + lane];
        unsigned v2 = h2[(size_t)s2 * 64 + lane];
        unsigned v3 = h2[(size_t)s3 * 64 + lane];
        x0 += __uint_as_float(v0 << 16); y0 += __uint_as_float(v0 & 0xffff0000u);
        x1 += __uint_as_float(v1 << 16); y1 += __uint_as_float(v1 & 0xffff0000u);
        x2 += __uint_as_float(v2 << 16); y2 += __uint_as_float(v2 & 0xffff0000u);
        x3 += __uint_as_float(v3 << 16); y3 += __uint_as_float(v3 & 0xffff0000u);
    }
    for (; p < e; ++p) {
        int s = srcs[p];
        unsigned v = h2[(size_t)s * 64 + lane];
        x0 += __uint_as_float(v << 16); y0 += __uint_as_float(v & 0xffff0000u);
    }
    float ax = (x0 + x1) + (x2 + x3);
    float ay = (y0 + y1) + (y2 + y3);
    unsigned o = (unsigned)f2bf(ax) | ((unsigned)f2bf(ay) << 16);
    ((unsigned*)aggb)[(size_t)wid * 64 + lane] = o;
}

// ------- MFMA GEMM layer 1: h1 = elu([agg1,x] @ Wb1^T + b1), 32x32x16, M=32/wave -------
__global__ __launch_bounds__(256) void g1_kernel(
    const ushort_t* __restrict__ aggb, const ushort_t* __restrict__ xb,
    const ushort_t* __restrict__ Wb1, const float* __restrict__ b1,
    ushort_t* __restrict__ h1b) {
    int wave = (blockIdx.x * 256 + threadIdx.x) >> 6;
    int lane = threadIdx.x & 63;
    int nb = wave << 5; // 32 nodes per wave
    if (nb >= N_NODES) return;
    int half = lane >> 5, col = lane & 31;
    int kh = half * 8;
    int nA = nb + col;
    if (nA >= N_NODES) nA = N_NODES - 1; // clamped rows never stored
    fx16 acc[4];
#pragma unroll
    for (int jt = 0; jt < 4; jt++)
#pragma unroll
        for (int r = 0; r < 16; r++) acc[jt][r] = 0.f;
#pragma unroll
    for (int s = 0; s < 8; s++) { // K = 128, 16 per step
        int k0 = s * 16 + kh;
        const short8* ap = (k0 < FIN)
            ? (const short8*)(aggb + (size_t)nA * FIN + k0)
            : (const short8*)(xb + (size_t)nA * FIN + (k0 - FIN));
        short8 a = *ap;
#pragma unroll
        for (int jt = 0; jt < 4; jt++) {
            short8 bq = *(const short8*)(Wb1 + (size_t)(jt * 32 + col) * HID + k0);
            acc[jt] = __builtin_amdgcn_mfma_f32_32x32x16_bf16(a, bq, acc[jt], 0, 0, 0);
        }
    }
#pragma unroll
    for (int jt = 0; jt < 4; jt++) {
        int j = jt * 32 + col;
        float bias = b1[j];
#pragma unroll
        for (int r = 0; r < 16; r++) {
            int node = nb + (r & 3) + 8 * (r >> 2) + 4 * half;
            if (node < N_NODES) {
                float v = acc[jt][r] + bias;
                v = v > 0.f ? v : __expf(v) - 1.f;
                h1b[(size_t)node * HID + j] = f2bf(v);
            }
        }
    }
}

// ------- MFMA GEMM layer 2: t2 = [agg2,h1] @ Wb2^T + b2, 32x32x16, M=32/wave -------
__global__ __launch_bounds__(256) void g2_kernel(
    const ushort_t* __restrict__ agg2b, const ushort_t* __restrict__ h1b,
    const ushort_t* __restrict__ Wb2, const float* __restrict__ b2,
    ushort_t* __restrict__ t2b) {
    int wave = (blockIdx.x * 256 + threadIdx.x) >> 6;
    int lane = threadIdx.x & 63;
    int nb = wave << 5;
    if (nb >= N_NODES) return;
    int half = lane >> 5, col = lane & 31;
    int kh = half * 8;
    int nA = nb + col;
    if (nA >= N_NODES) nA = N_NODES - 1;
    fx16 acc[4];
#pragma unroll
    for (int jt = 0; jt < 4; jt++)
#pragma unroll
        for (int r = 0; r < 16; r++) acc[jt][r] = 0.f;
#pragma unroll
    for (int s = 0; s < 16; s++) { // K = 256, 16 per step
        int k0 = s * 16 + kh;
        const short8* ap = (k0 < HID)
            ? (const short8*)(agg2b + (size_t)nA * HID + k0)
            : (const short8*)(h1b + (size_t)nA * HID + (k0 - HID));
        short8 a = *ap;
#pragma unroll
        for (int jt = 0; jt < 4; jt++) {
            short8 bq = *(const short8*)(Wb2 + (size_t)(jt * 32 + col) * (2 * HID) + k0);
            acc[jt] = __builtin_amdgcn_mfma_f32_32x32x16_bf16(a, bq, acc[jt], 0, 0, 0);
        }
    }
#pragma unroll
    for (int jt = 0; jt < 4; jt++) {
        int j = jt * 32 + col;
        float bias = b2[j];
#pragma unroll
        for (int r = 0; r < 16; r++) {
            int node = nb + (r & 3) + 8 * (r >> 2) + 4 * half;
            if (node < N_NODES) {
                float v = acc[jt][r] + bias;
                t2b[(size_t)node * HID + j] = f2bf(v);
            }
        }
    }
}

// ---------------- fused MLP head: out = fc2(relu(fc1(t2))) ----------------
__global__ __launch_bounds__(256) void head_kernel(
    const ushort_t* __restrict__ t2b, const float* __restrict__ Wfc1,
    const float* __restrict__ bfc1, const float* __restrict__ Wfc2,
    const float* __restrict__ bfc2, float* __restrict__ out) {
    int i = blockIdx.x * 256 + threadIdx.x;
    if (i >= N_NODES) return;
    float g[20];
#pragma unroll
    for (int m = 0; m < 20; m++) g[m] = 0.f;
    const uint4* row = (const uint4*)(t2b + (size_t)i * HID);
    for (int c = 0; c < 16; c++) { // 16 chunks of 8 features
        uint4 v = row[c];
        float f0 = __uint_as_float(v.x << 16), f1 = __uint_as_float(v.x & 0xffff0000u);
        float f2 = __uint_as_float(v.y << 16), f3 = __uint_as_float(v.y & 0xffff0000u);
        float f4 = __uint_as_float(v.z << 16), f5 = __uint_as_float(v.z & 0xffff0000u);
        float f6 = __uint_as_float(v.w << 16), f7 = __uint_as_float(v.w & 0xffff0000u);
        int j = c * 8;
#pragma unroll
        for (int m = 0; m < 20; m++) {
            const float* w = Wfc1 + m * HID + j; // j,m uniform -> s_loads
            g[m] += f0 * w[0] + f1 * w[1] + f2 * w[2] + f3 * w[3] +
                    f4 * w[4] + f5 * w[5] + f6 * w[6] + f7 * w[7];
        }
    }
    float o = bfc2[0];
#pragma unroll
    for (int m = 0; m < 20; m++) {
        float gm = g[m] + bfc1[m];
        o += (gm > 0.f ? gm : 0.f) * Wfc2[m];
    }
    out[i] = o;
}

// ---------------- launch ----------------
extern "C" void kernel_launch(void* const* d_in, const int* in_sizes, int n_in,
                              void* d_out, int out_size, void* d_ws, size_t ws_size,
                              hipStream_t stream) {
    const float* x = (const float*)d_in[0];
    const int* ei = (const int*)d_in[1];
    const float* W1rel = (const float*)d_in[2];
    const float* b1 = (const float*)d_in[3];
    const float* W1root = (const float*)d_in[4];
    const float* W2rel = (const float*)d_in[5];
    const float* b2 = (const float*)d_in[6];
    const float* W2root = (const float*)d_in[7];
    const float* Wfc1 = (const float*)d_in[8];
    const float* bfc1 = (const float*)d_in[9];
    const float* Wfc2 = (const float*)d_in[10];
    const float* bfc2 = (const float*)d_in[11];
    float* out = (float*)d_out;

    char* ws = (char*)d_ws;
    size_t o = 0;
    int* deg = (int*)(ws + o);       o += (size_t)N_NODES * 4;
    int* off = (int*)(ws + o);       o += (size_t)(N_NODES + 1) * 4 + 12;
    int* bsums = (int*)(ws + o);     o += 4096;
    int* flag = (int*)(ws + o);      o += 16;
    int* rank = (int*)(ws + o);      o += (size_t)N_EDGES * 4;          // 3.2 MB
    int* srcs = (int*)(ws + o);      o += (size_t)N_EDGES * 4;          // 3.2 MB
    ushort_t* xb = (ushort_t*)(ws + o);    o += (size_t)N_NODES * FIN * 2;  // 12.8 MB
    ushort_t* agg1b = (ushort_t*)(ws + o); o += (size_t)N_NODES * FIN * 2;  // 12.8 MB
    ushort_t* h1b = (ushort_t*)(ws + o);   o += (size_t)N_NODES * HID * 2;  // 25.6 MB
    ushort_t* agg2b = (ushort_t*)(ws + o); o += (size_t)N_NODES * HID * 2;  // 25.6 MB
    ushort_t* t2b = (ushort_t*)(ws + o);   o += (size_t)N_NODES * HID * 2;  // 25.6 MB
    ushort_t* Wb1 = (ushort_t*)(ws + o);   o += (size_t)HID * HID * 2;      // 32 KB
    ushort_t* Wb2 = (ushort_t*)(ws + o);   o += (size_t)HID * 2 * HID * 2;  // 64 KB

    const int GW = (N_NODES + 127) / 128; // 782 blocks: 4 waves x 32 nodes per block

    zero_int_kernel<<<NB1, 256, 0, stream>>>(deg, N_NODES);
    zero_int_kernel<<<1, 256, 0, stream>>>(flag, 1);
    detect_kernel<<<32, 256, 0, stream>>>(ei, flag);
    hist_kernel<<<(N_EDGES + 255) / 256, 256, 0, stream>>>(ei, flag, deg, rank);
    scan1_kernel<<<NB1, 256, 0, stream>>>(deg, off, bsums);
    scan2_kernel<<<1, 512, 0, stream>>>(bsums);
    scan3_kernel<<<NB1, 256, 0, stream>>>(off, bsums);
    scatter_kernel<<<(N_EDGES + 255) / 256, 256, 0, stream>>>(ei, flag, off, rank, srcs);
    xcvt_kernel<<<(N_NODES * FIN / 4 + 255) / 256, 256, 0, stream>>>(x, xb);
    wcvt_kernel<<<(HID * 2 * HID + 255) / 256, 256, 0, stream>>>(W1rel, W1root, W2rel, W2root, Wb1, Wb2);
    agg1_kernel<<<N_NODES / 4, 256, 0, stream>>>(xb, off, srcs, agg1b);
    g1_kernel<<<GW, 256, 0, stream>>>(agg1b, xb, Wb1, b1, h1b);
    agg2_kernel<<<N_NODES / 4, 256, 0, stream>>>(h1b, off, srcs, agg2b);
    g2_kernel<<<GW, 256, 0, stream>>>(agg2b, h1b, Wb2, b2, t2b);
    head_kernel<<<NB1, 256, 0, stream>>>(t2b, Wfc1, bfc1, Wfc2, bfc2, out);
}

// Round 6
// 288.346 us; speedup vs baseline: 5.7931x; 1.1448x over previous
//
#include <hip/hip_runtime.h>

#define N_NODES 100000
#define N_EDGES 800000
#define FIN 64
#define HID 128
#define NB1 391   // ceil(N_NODES/256)

typedef unsigned short ushort_t;
typedef __attribute__((ext_vector_type(8))) short short8;   // 8 bf16 = 4 VGPRs (MFMA A/B frag)
typedef __attribute__((ext_vector_type(16))) float fx16;    // 32x32 MFMA C/D frag
typedef __attribute__((ext_vector_type(4))) unsigned short us4;

__device__ inline ushort_t f2bf(float f) {   // RNE fp32 -> bf16
    unsigned u = __float_as_uint(f);
    u += 0x7fffu + ((u >> 16) & 1u);
    return (ushort_t)(u >> 16);
}
__device__ inline float bf2f(ushort_t h) { return __uint_as_float(((unsigned)h) << 16); }

// ---------------- utility ----------------
__global__ void zero_int_kernel(int* __restrict__ p, int n) {
    int i = blockIdx.x * 256 + threadIdx.x;
    if (i < n) p[i] = 0;
}

// int32 vs int64 edge_index layout probe (int64 little-endian => odd words all 0)
__global__ void detect_kernel(const int* __restrict__ w, int* __restrict__ flag) {
    int i = blockIdx.x * 256 + threadIdx.x;
    if (i < 8192) {
        if (w[2 * i + 1] != 0) atomicOr(flag, 1);
    }
}

// ---------------- CSR build ----------------
__global__ void hist_kernel(const int* __restrict__ w, const int* __restrict__ flag,
                            int* __restrict__ deg, int* __restrict__ rank) {
    int e = blockIdx.x * 256 + threadIdx.x;
    if (e >= N_EDGES) return;
    int is32 = *flag;
    int d = is32 ? w[N_EDGES + e] : w[2 * (N_EDGES + e)];
    rank[e] = atomicAdd(&deg[d], 1);
}

__global__ void scan1_kernel(const int* __restrict__ deg, int* __restrict__ off,
                             int* __restrict__ bsums) {
    __shared__ int s[256];
    int t = threadIdx.x;
    int i = blockIdx.x * 256 + t;
    int v = (i < N_NODES) ? deg[i] : 0;
    s[t] = v;
    __syncthreads();
    for (int d = 1; d < 256; d <<= 1) {
        int w = (t >= d) ? s[t - d] : 0;
        __syncthreads();
        s[t] += w;
        __syncthreads();
    }
    if (i < N_NODES) off[i] = s[t] - v;
    if (t == 255) bsums[blockIdx.x] = s[255];
}

__global__ void scan2_kernel(int* __restrict__ bsums) {
    __shared__ int s[512];
    int t = threadIdx.x;
    int v = (t < NB1) ? bsums[t] : 0;
    s[t] = v;
    __syncthreads();
    for (int d = 1; d < 512; d <<= 1) {
        int w = (t >= d) ? s[t - d] : 0;
        __syncthreads();
        s[t] += w;
        __syncthreads();
    }
    if (t < NB1) bsums[t] = s[t] - v;
}

__global__ void scan3_kernel(int* __restrict__ off, const int* __restrict__ bsums) {
    int i = blockIdx.x * 256 + threadIdx.x;
    if (i < N_NODES) off[i] = off[i] + bsums[blockIdx.x];
    if (i == 0) off[N_NODES] = N_EDGES;
}

__global__ void scatter_kernel(const int* __restrict__ w, const int* __restrict__ flag,
                               const int* __restrict__ off, const int* __restrict__ rank,
                               int* __restrict__ srcs) {
    int e = blockIdx.x * 256 + threadIdx.x;
    if (e >= N_EDGES) return;
    int is32 = *flag;
    int s = is32 ? w[e] : w[2 * e];
    int d = is32 ? w[N_EDGES + e] : w[2 * (N_EDGES + e)];
    srcs[off[d] + rank[e]] = s;
}

// ---------------- dtype conversion ----------------
__global__ void xcvt_kernel(const float* __restrict__ x, ushort_t* __restrict__ xb) {
    int i = blockIdx.x * 256 + threadIdx.x; // quad id
    if (i >= N_NODES * FIN / 4) return;
    float4 v = ((const float4*)x)[i];
    us4 o = {f2bf(v.x), f2bf(v.y), f2bf(v.z), f2bf(v.w)};
    ((us4*)xb)[i] = o;
}

// Wb1[n][k], k<64 -> W1rel, else W1root. Wb2[n][k], k<128 -> W2rel, else W2root.
__global__ void wcvt_kernel(const float* __restrict__ W1rel, const float* __restrict__ W1root,
                            const float* __restrict__ W2rel, const float* __restrict__ W2root,
                            ushort_t* __restrict__ Wb1, ushort_t* __restrict__ Wb2) {
    int i = blockIdx.x * 256 + threadIdx.x;
    if (i < HID * HID) {
        int n = i >> 7, k = i & 127;
        float v = (k < FIN) ? W1rel[n * FIN + k] : W1root[n * FIN + (k - FIN)];
        Wb1[i] = f2bf(v);
    }
    if (i < HID * 2 * HID) {
        int n = i >> 8, k = i & 255;
        float v = (k < HID) ? W2rel[n * HID + k] : W2root[n * HID + (k - HID)];
        Wb2[i] = f2bf(v);
    }
}

// ------- aggregation (CSR gather, one wave per node, x4 unrolled for MLP) -------
__global__ void agg1_kernel(const ushort_t* __restrict__ xb, const int* __restrict__ off,
                            const int* __restrict__ srcs, ushort_t* __restrict__ aggb) {
    int wid = (blockIdx.x * 256 + threadIdx.x) >> 6; // node
    int lane = threadIdx.x & 63;                     // feature
    if (wid >= N_NODES) return;
    int b = __builtin_amdgcn_readfirstlane(off[wid]);
    int e = __builtin_amdgcn_readfirstlane(off[wid + 1]);
    float a0 = 0.f, a1 = 0.f, a2 = 0.f, a3 = 0.f;
    int p = b;
    for (; p + 4 <= e; p += 4) {
        int s0 = srcs[p], s1 = srcs[p + 1], s2 = srcs[p + 2], s3 = srcs[p + 3];
        a0 += bf2f(xb[(size_t)s0 * FIN + lane]);
        a1 += bf2f(xb[(size_t)s1 * FIN + lane]);
        a2 += bf2f(xb[(size_t)s2 * FIN + lane]);
        a3 += bf2f(xb[(size_t)s3 * FIN + lane]);
    }
    for (; p < e; ++p) {
        int s = srcs[p];
        a0 += bf2f(xb[(size_t)s * FIN + lane]);
    }
    aggb[(size_t)wid * FIN + lane] = f2bf((a0 + a1) + (a2 + a3));
}

__global__ void agg2_kernel(const ushort_t* __restrict__ h1b, const int* __restrict__ off,
                            const int* __restrict__ srcs, ushort_t* __restrict__ aggb) {
    int wid = (blockIdx.x * 256 + threadIdx.x) >> 6; // node
    int lane = threadIdx.x & 63;                     // 2 features per lane
    if (wid >= N_NODES) return;
    int b = __builtin_amdgcn_readfirstlane(off[wid]);
    int e = __builtin_amdgcn_readfirstlane(off[wid + 1]);
    const unsigned* h2 = (const unsigned*)h1b;
    float x0 = 0.f, y0 = 0.f, x1 = 0.f, y1 = 0.f;
    float x2 = 0.f, y2 = 0.f, x3 = 0.f, y3 = 0.f;
    int p = b;
    for (; p + 4 <= e; p += 4) {
        int s0 = srcs[p], s1 = srcs[p + 1], s2 = srcs[p + 2], s3 = srcs[p + 3];
        unsigned v0 = h2[(size_t)s0 * 64 + lane];
        unsigned v1 = h2[(size_t)s1 * 64 + lane];
        unsigned v2 = h2[(size_t)s2 * 64 + lane];
        unsigned v3 = h2[(size_t)s3 * 64 + lane];
        x0 += __uint_as_float(v0 << 16); y0 += __uint_as_float(v0 & 0xffff0000u);
        x1 += __uint_as_float(v1 << 16); y1 += __uint_as_float(v1 & 0xffff0000u);
        x2 += __uint_as_float(v2 << 16); y2 += __uint_as_float(v2 & 0xffff0000u);
        x3 += __uint_as_float(v3 << 16); y3 += __uint_as_float(v3 & 0xffff0000u);
    }
    for (; p < e; ++p) {
        int s = srcs[p];
        unsigned v = h2[(size_t)s * 64 + lane];
        x0 += __uint_as_float(v << 16); y0 += __uint_as_float(v & 0xffff0000u);
    }
    float ax = (x0 + x1) + (x2 + x3);
    float ay = (y0 + y1) + (y2 + y3);
    unsigned o = (unsigned)f2bf(ax) | ((unsigned)f2bf(ay) << 16);
    ((unsigned*)aggb)[(size_t)wid * 64 + lane] = o;
}

// ------- MFMA GEMM layer 1: h1 = elu([agg1,x] @ Wb1^T + b1) -------
// Weights in LDS (32 KB, XOR-chunk swizzle => conflict-free ds_read_b128),
// A-fragments prefetched to registers (8 independent 16B loads in flight).
__global__ __launch_bounds__(256) void g1_kernel(
    const ushort_t* __restrict__ aggb, const ushort_t* __restrict__ xb,
    const ushort_t* __restrict__ Wb1, const float* __restrict__ b1,
    ushort_t* __restrict__ h1b) {
    __shared__ short8 wl8[2048];                 // 32 KB
    ushort_t* wl = (ushort_t*)wl8;
    // stage: chunk q (16B) of row n=q>>4, c=q&15 -> position c ^ (n&7)
#pragma unroll
    for (int it = 0; it < 8; it++) {
        int q = it * 256 + threadIdx.x;
        int n = q >> 4, c = q & 15;
        short8 v = ((const short8*)Wb1)[q];
        *(short8*)(wl + n * HID + ((c ^ (n & 7)) << 3)) = v;
    }
    __syncthreads();

    int wave = threadIdx.x >> 6;
    int lane = threadIdx.x & 63;
    int nb = blockIdx.x * 128 + wave * 32;
    if (nb >= N_NODES) return;   // after the only barrier
    int half = lane >> 5, col = lane & 31;
    int nA = nb + col;
    if (nA >= N_NODES) nA = N_NODES - 1;

    short8 areg[8];
#pragma unroll
    for (int s = 0; s < 4; s++)
        areg[s] = *(const short8*)(aggb + (size_t)nA * FIN + s * 16 + half * 8);
#pragma unroll
    for (int s = 4; s < 8; s++)
        areg[s] = *(const short8*)(xb + (size_t)nA * FIN + (s - 4) * 16 + half * 8);

    fx16 acc[4];
#pragma unroll
    for (int jt = 0; jt < 4; jt++)
#pragma unroll
        for (int r = 0; r < 16; r++) acc[jt][r] = 0.f;

#pragma unroll
    for (int s = 0; s < 8; s++) {
        int c = 2 * s + half;
#pragma unroll
        for (int jt = 0; jt < 4; jt++) {
            int n = jt * 32 + col;
            short8 bq = *(const short8*)(wl + n * HID + ((c ^ (n & 7)) << 3));
            acc[jt] = __builtin_amdgcn_mfma_f32_32x32x16_bf16(areg[s], bq, acc[jt], 0, 0, 0);
        }
    }
#pragma unroll
    for (int jt = 0; jt < 4; jt++) {
        int j = jt * 32 + col;
        float bias = b1[j];
#pragma unroll
        for (int r = 0; r < 16; r++) {
            int node = nb + (r & 3) + 8 * (r >> 2) + 4 * half;
            if (node < N_NODES) {
                float v = acc[jt][r] + bias;
                v = v > 0.f ? v : __expf(v) - 1.f;
                h1b[(size_t)node * HID + j] = f2bf(v);
            }
        }
    }
}

// ------- MFMA GEMM layer 2 + fused MLP head -------
// Phase 1: t2 = [agg2,h1] @ Wb2^T + b2 (weights in 64 KB LDS, swizzled).
// Phase 2: LDS tile [j][node_local] bf16 (stride 132) — node_local INCLUDES wave*32
//          (R5 bug: offset was missing -> all waves overwrote rows 0..31).
//          Then out = fc2(relu(fc1(t2))) with 2 threads/node (j-halves), s_load Wfc1.
__global__ __launch_bounds__(256) void g2h_kernel(
    const ushort_t* __restrict__ agg2b, const ushort_t* __restrict__ h1b,
    const ushort_t* __restrict__ Wb2, const float* __restrict__ b2,
    const float* __restrict__ Wfc1, const float* __restrict__ bfc1,
    const float* __restrict__ Wfc2, const float* __restrict__ bfc2,
    float* __restrict__ out) {
    __shared__ short8 smem8[4096];               // 64 KB, reused across phases
    ushort_t* wl = (ushort_t*)smem8;
    // stage Wb2: 4096 chunks, swizzle c -> c ^ (n&7)
#pragma unroll
    for (int it = 0; it < 16; it++) {
        int q = it * 256 + threadIdx.x;
        int n = q >> 5, c = q & 31;
        short8 v = ((const short8*)Wb2)[q];
        *(short8*)(wl + n * 256 + ((c ^ (n & 7)) << 3)) = v;
    }
    __syncthreads();

    int wave = threadIdx.x >> 6;
    int lane = threadIdx.x & 63;
    int half = lane >> 5, col = lane & 31;
    int nb = blockIdx.x * 128 + wave * 32;       // may be >= N for tail waves: keep running (barriers!)
    int nA = nb + col;
    if (nA >= N_NODES) nA = N_NODES - 1;

    short8 areg[16];
#pragma unroll
    for (int s = 0; s < 8; s++)
        areg[s] = *(const short8*)(agg2b + (size_t)nA * HID + s * 16 + half * 8);
#pragma unroll
    for (int s = 8; s < 16; s++)
        areg[s] = *(const short8*)(h1b + (size_t)nA * HID + (s - 8) * 16 + half * 8);

    fx16 acc[4];
#pragma unroll
    for (int jt = 0; jt < 4; jt++)
#pragma unroll
        for (int r = 0; r < 16; r++) acc[jt][r] = 0.f;

#pragma unroll
    for (int s = 0; s < 16; s++) {
        int c = 2 * s + half;
#pragma unroll
        for (int jt = 0; jt < 4; jt++) {
            int n = jt * 32 + col;
            short8 bq = *(const short8*)(wl + n * 256 + ((c ^ (n & 7)) << 3));
            acc[jt] = __builtin_amdgcn_mfma_f32_32x32x16_bf16(areg[s], bq, acc[jt], 0, 0, 0);
        }
    }
    __syncthreads();   // all waves done reading weights; LDS now reused for t2 tile

    // tile [j][node_local], bf16, stride 132 (2-way bank aliasing only = free)
    ushort_t* tl = (ushort_t*)smem8;
#pragma unroll
    for (int jt = 0; jt < 4; jt++) {
        int j = jt * 32 + col;
        float bias = b2[j];
#pragma unroll
        for (int rc = 0; rc < 4; rc++) {
            int n0 = wave * 32 + rc * 8 + 4 * half;  // local node = wave offset + C/D row
            us4 pack = {f2bf(acc[jt][rc * 4 + 0] + bias),
                        f2bf(acc[jt][rc * 4 + 1] + bias),
                        f2bf(acc[jt][rc * 4 + 2] + bias),
                        f2bf(acc[jt][rc * 4 + 3] + bias)};
            *(us4*)(tl + j * 132 + n0) = pack;
        }
    }
    __syncthreads();

    // head: thread t -> node (t&127), j-half (t>>7) [wave-uniform -> s_load Wfc1]
    int t = threadIdx.x;
    int n = t & 127;
    int jh = __builtin_amdgcn_readfirstlane(t >> 7);
    int j0 = jh * 64;
    float g[20];
#pragma unroll
    for (int m = 0; m < 20; m++) g[m] = 0.f;
    for (int jj = 0; jj < 64; jj++) {
        int j = j0 + jj;
        float tv = bf2f(tl[j * 132 + n]);
#pragma unroll
        for (int m = 0; m < 20; m++) g[m] += tv * Wfc1[m * HID + j];
    }
    float* gp = (float*)((char*)smem8 + 36864);  // partials, after tile (33792 B)
    if (t >= 128) {
#pragma unroll
        for (int m = 0; m < 20; m++) gp[(t - 128) * 20 + m] = g[m];
    }
    __syncthreads();
    if (t < 128) {
        int ng = blockIdx.x * 128 + n;
        if (ng < N_NODES) {
            float o = bfc2[0];
#pragma unroll
            for (int m = 0; m < 20; m++) {
                float gm = g[m] + gp[t * 20 + m] + bfc1[m];
                o += (gm > 0.f ? gm : 0.f) * Wfc2[m];
            }
            out[ng] = o;
        }
    }
}

// ---------------- launch ----------------
extern "C" void kernel_launch(void* const* d_in, const int* in_sizes, int n_in,
                              void* d_out, int out_size, void* d_ws, size_t ws_size,
                              hipStream_t stream) {
    const float* x = (const float*)d_in[0];
    const int* ei = (const int*)d_in[1];
    const float* W1rel = (const float*)d_in[2];
    const float* b1 = (const float*)d_in[3];
    const float* W1root = (const float*)d_in[4];
    const float* W2rel = (const float*)d_in[5];
    const float* b2 = (const float*)d_in[6];
    const float* W2root = (const float*)d_in[7];
    const float* Wfc1 = (const float*)d_in[8];
    const float* bfc1 = (const float*)d_in[9];
    const float* Wfc2 = (const float*)d_in[10];
    const float* bfc2 = (const float*)d_in[11];
    float* out = (float*)d_out;

    char* ws = (char*)d_ws;
    size_t o = 0;
    int* deg = (int*)(ws + o);       o += (size_t)N_NODES * 4;
    int* off = (int*)(ws + o);       o += (size_t)(N_NODES + 1) * 4 + 12;
    int* bsums = (int*)(ws + o);     o += 4096;
    int* flag = (int*)(ws + o);      o += 16;
    int* rank = (int*)(ws + o);      o += (size_t)N_EDGES * 4;          // 3.2 MB
    int* srcs = (int*)(ws + o);      o += (size_t)N_EDGES * 4;          // 3.2 MB
    ushort_t* xb = (ushort_t*)(ws + o);    o += (size_t)N_NODES * FIN * 2;  // 12.8 MB
    ushort_t* agg1b = (ushort_t*)(ws + o); o += (size_t)N_NODES * FIN * 2;  // 12.8 MB
    ushort_t* h1b = (ushort_t*)(ws + o);   o += (size_t)N_NODES * HID * 2;  // 25.6 MB
    ushort_t* agg2b = (ushort_t*)(ws + o); o += (size_t)N_NODES * HID * 2;  // 25.6 MB
    ushort_t* Wb1 = (ushort_t*)(ws + o);   o += (size_t)HID * HID * 2;      // 32 KB
    ushort_t* Wb2 = (ushort_t*)(ws + o);   o += (size_t)HID * 2 * HID * 2;  // 64 KB

    const int GW = (N_NODES + 127) / 128; // 782 blocks: 4 waves x 32 nodes

    zero_int_kernel<<<NB1, 256, 0, stream>>>(deg, N_NODES);
    zero_int_kernel<<<1, 256, 0, stream>>>(flag, 1);
    detect_kernel<<<32, 256, 0, stream>>>(ei, flag);
    hist_kernel<<<(N_EDGES + 255) / 256, 256, 0, stream>>>(ei, flag, deg, rank);
    scan1_kernel<<<NB1, 256, 0, stream>>>(deg, off, bsums);
    scan2_kernel<<<1, 512, 0, stream>>>(bsums);
    scan3_kernel<<<NB1, 256, 0, stream>>>(off, bsums);
    scatter_kernel<<<(N_EDGES + 255) / 256, 256, 0, stream>>>(ei, flag, off, rank, srcs);
    xcvt_kernel<<<(N_NODES * FIN / 4 + 255) / 256, 256, 0, stream>>>(x, xb);
    wcvt_kernel<<<(HID * 2 * HID + 255) / 256, 256, 0, stream>>>(W1rel, W1root, W2rel, W2root, Wb1, Wb2);
    agg1_kernel<<<N_NODES / 4, 256, 0, stream>>>(xb, off, srcs, agg1b);
    g1_kernel<<<GW, 256, 0, stream>>>(agg1b, xb, Wb1, b1, h1b);
    agg2_kernel<<<N_NODES / 4, 256, 0, stream>>>(h1b, off, srcs, agg2b);
    g2h_kernel<<<GW, 256, 0, stream>>>(agg2b, h1b, Wb2, b2, Wfc1, bfc1, Wfc2, bfc2, out);
}

// Round 7
// 287.277 us; speedup vs baseline: 5.8146x; 1.0037x over previous
//
#include <hip/hip_runtime.h>

#define N_NODES 100000
#define N_EDGES 800000
#define FIN 64
#define HID 128
#define NB1 391   // ceil(N_NODES/256)

typedef unsigned short ushort_t;
typedef __attribute__((ext_vector_type(8))) short short8;   // 8 bf16 = 4 VGPRs (MFMA A/B frag)
typedef __attribute__((ext_vector_type(16))) float fx16;    // 32x32 MFMA C/D frag
typedef __attribute__((ext_vector_type(4))) unsigned short us4;

__device__ inline ushort_t f2bf(float f) {   // RNE fp32 -> bf16
    unsigned u = __float_as_uint(f);
    u += 0x7fffu + ((u >> 16) & 1u);
    return (ushort_t)(u >> 16);
}
__device__ inline float bf2f(ushort_t h) { return __uint_as_float(((unsigned)h) << 16); }

// ---------------- utility ----------------
__global__ void zero_int_kernel(int* __restrict__ p, int n) {
    int i = blockIdx.x * 256 + threadIdx.x;
    if (i < n) p[i] = 0;
}

// int32 vs int64 edge_index layout probe (int64 little-endian => odd words all 0)
__global__ void detect_kernel(const int* __restrict__ w, int* __restrict__ flag) {
    int i = blockIdx.x * 256 + threadIdx.x;
    if (i < 8192) {
        if (w[2 * i + 1] != 0) atomicOr(flag, 1);
    }
}

// ---------------- CSR build ----------------
__global__ void hist_kernel(const int* __restrict__ w, const int* __restrict__ flag,
                            int* __restrict__ deg, int* __restrict__ rank) {
    int e = blockIdx.x * 256 + threadIdx.x;
    if (e >= N_EDGES) return;
    int is32 = *flag;
    int d = is32 ? w[N_EDGES + e] : w[2 * (N_EDGES + e)];
    rank[e] = atomicAdd(&deg[d], 1);
}

__global__ void scan1_kernel(const int* __restrict__ deg, int* __restrict__ off,
                             int* __restrict__ bsums) {
    __shared__ int s[256];
    int t = threadIdx.x;
    int i = blockIdx.x * 256 + t;
    int v = (i < N_NODES) ? deg[i] : 0;
    s[t] = v;
    __syncthreads();
    for (int d = 1; d < 256; d <<= 1) {
        int w = (t >= d) ? s[t - d] : 0;
        __syncthreads();
        s[t] += w;
        __syncthreads();
    }
    if (i < N_NODES) off[i] = s[t] - v;
    if (t == 255) bsums[blockIdx.x] = s[255];
}

__global__ void scan2_kernel(int* __restrict__ bsums) {
    __shared__ int s[512];
    int t = threadIdx.x;
    int v = (t < NB1) ? bsums[t] : 0;
    s[t] = v;
    __syncthreads();
    for (int d = 1; d < 512; d <<= 1) {
        int w = (t >= d) ? s[t - d] : 0;
        __syncthreads();
        s[t] += w;
        __syncthreads();
    }
    if (t < NB1) bsums[t] = s[t] - v;
}

__global__ void scan3_kernel(int* __restrict__ off, const int* __restrict__ bsums) {
    int i = blockIdx.x * 256 + threadIdx.x;
    if (i < N_NODES) off[i] = off[i] + bsums[blockIdx.x];
    if (i == 0) off[N_NODES] = N_EDGES;
}

__global__ void scatter_kernel(const int* __restrict__ w, const int* __restrict__ flag,
                               const int* __restrict__ off, const int* __restrict__ rank,
                               int* __restrict__ srcs) {
    int e = blockIdx.x * 256 + threadIdx.x;
    if (e >= N_EDGES) return;
    int is32 = *flag;
    int s = is32 ? w[e] : w[2 * e];
    int d = is32 ? w[N_EDGES + e] : w[2 * (N_EDGES + e)];
    srcs[off[d] + rank[e]] = s;
}

// ---------------- dtype conversion ----------------
__global__ void xcvt_kernel(const float* __restrict__ x, ushort_t* __restrict__ xb) {
    int i = blockIdx.x * 256 + threadIdx.x; // quad id
    if (i >= N_NODES * FIN / 4) return;
    float4 v = ((const float4*)x)[i];
    us4 o = {f2bf(v.x), f2bf(v.y), f2bf(v.z), f2bf(v.w)};
    ((us4*)xb)[i] = o;
}

// Wb1[n][k], k<64 -> W1rel, else W1root. Wb2[n][k], k<128 -> W2rel, else W2root.
__global__ void wcvt_kernel(const float* __restrict__ W1rel, const float* __restrict__ W1root,
                            const float* __restrict__ W2rel, const float* __restrict__ W2root,
                            ushort_t* __restrict__ Wb1, ushort_t* __restrict__ Wb2) {
    int i = blockIdx.x * 256 + threadIdx.x;
    if (i < HID * HID) {
        int n = i >> 7, k = i & 127;
        float v = (k < FIN) ? W1rel[n * FIN + k] : W1root[n * FIN + (k - FIN)];
        Wb1[i] = f2bf(v);
    }
    if (i < HID * 2 * HID) {
        int n = i >> 8, k = i & 255;
        float v = (k < HID) ? W2rel[n * HID + k] : W2root[n * HID + (k - HID)];
        Wb2[i] = f2bf(v);
    }
}

// ------- aggregation: wave per node, slot-parallel vectorized gather -------
// agg1: x rows are 128 B = 8 uint4 chunks. lane -> (slot g = lane>>3, chunk c = lane&7).
// One wave instruction gathers 8 edges (1 KiB). Butterfly ^8,^16,^32 combines slots.
__global__ void agg1_kernel(const ushort_t* __restrict__ xb, const int* __restrict__ off,
                            const int* __restrict__ srcs, ushort_t* __restrict__ aggb) {
    int wid = (blockIdx.x * 256 + threadIdx.x) >> 6; // node
    int lane = threadIdx.x & 63;
    if (wid >= N_NODES) return;
    int b = __builtin_amdgcn_readfirstlane(off[wid]);
    int e = __builtin_amdgcn_readfirstlane(off[wid + 1]);
    int g = lane >> 3;   // edge slot 0..7
    int c = lane & 7;    // 16B chunk of the 128B row
    float acc[8];
#pragma unroll
    for (int j = 0; j < 8; j++) acc[j] = 0.f;
    const uint4* rows = (const uint4*)xb;    // 8 chunks per row
    for (int p = b; p < e; p += 8) {
        int i0 = p + g;
        bool q0 = i0 < e;
        int s0 = srcs[q0 ? i0 : e - 1];      // clamped: always in-bounds, real data
        uint4 A = rows[(size_t)s0 * 8 + c];
        unsigned a0 = q0 ? A.x : 0u, a1 = q0 ? A.y : 0u;
        unsigned a2 = q0 ? A.z : 0u, a3 = q0 ? A.w : 0u;
        acc[0] += __uint_as_float(a0 << 16);
        acc[1] += __uint_as_float(a0 & 0xffff0000u);
        acc[2] += __uint_as_float(a1 << 16);
        acc[3] += __uint_as_float(a1 & 0xffff0000u);
        acc[4] += __uint_as_float(a2 << 16);
        acc[5] += __uint_as_float(a2 & 0xffff0000u);
        acc[6] += __uint_as_float(a3 << 16);
        acc[7] += __uint_as_float(a3 & 0xffff0000u);
    }
#pragma unroll
    for (int j = 0; j < 8; j++) {
        acc[j] += __shfl_xor(acc[j], 8);
        acc[j] += __shfl_xor(acc[j], 16);
        acc[j] += __shfl_xor(acc[j], 32);
    }
    if (lane < 8) {
        unsigned w0 = (unsigned)f2bf(acc[0]) | ((unsigned)f2bf(acc[1]) << 16);
        unsigned w1 = (unsigned)f2bf(acc[2]) | ((unsigned)f2bf(acc[3]) << 16);
        unsigned w2 = (unsigned)f2bf(acc[4]) | ((unsigned)f2bf(acc[5]) << 16);
        unsigned w3 = (unsigned)f2bf(acc[6]) | ((unsigned)f2bf(acc[7]) << 16);
        uint4 o = {w0, w1, w2, w3};
        ((uint4*)(aggb + (size_t)wid * FIN))[lane] = o;
    }
}

// agg2: h1 rows are 256 B = 16 uint4 chunks. lane -> (slot g = lane>>4, chunk c = lane&15).
// 4 edges per instruction; 2 groups unrolled (8 edges, 2 KiB in flight). Butterfly ^16,^32.
__global__ void agg2_kernel(const ushort_t* __restrict__ h1b, const int* __restrict__ off,
                            const int* __restrict__ srcs, ushort_t* __restrict__ aggb) {
    int wid = (blockIdx.x * 256 + threadIdx.x) >> 6; // node
    int lane = threadIdx.x & 63;
    if (wid >= N_NODES) return;
    int b = __builtin_amdgcn_readfirstlane(off[wid]);
    int e = __builtin_amdgcn_readfirstlane(off[wid + 1]);
    int g = lane >> 4;   // edge slot 0..3
    int c = lane & 15;   // 16B chunk of the 256B row
    float acc[8];
#pragma unroll
    for (int j = 0; j < 8; j++) acc[j] = 0.f;
    const uint4* rows = (const uint4*)h1b;   // 16 chunks per row
    for (int p = b; p < e; p += 8) {
        int i0 = p + g, i1 = p + 4 + g;
        bool q0 = i0 < e, q1 = i1 < e;
        int s0 = srcs[q0 ? i0 : e - 1];
        int s1 = srcs[q1 ? i1 : e - 1];
        uint4 A = rows[(size_t)s0 * 16 + c];
        uint4 B = rows[(size_t)s1 * 16 + c];
        unsigned a0 = q0 ? A.x : 0u, a1 = q0 ? A.y : 0u;
        unsigned a2 = q0 ? A.z : 0u, a3 = q0 ? A.w : 0u;
        unsigned b0 = q1 ? B.x : 0u, b1v = q1 ? B.y : 0u;
        unsigned b2v = q1 ? B.z : 0u, b3v = q1 ? B.w : 0u;
        acc[0] += __uint_as_float(a0 << 16) + __uint_as_float(b0 << 16);
        acc[1] += __uint_as_float(a0 & 0xffff0000u) + __uint_as_float(b0 & 0xffff0000u);
        acc[2] += __uint_as_float(a1 << 16) + __uint_as_float(b1v << 16);
        acc[3] += __uint_as_float(a1 & 0xffff0000u) + __uint_as_float(b1v & 0xffff0000u);
        acc[4] += __uint_as_float(a2 << 16) + __uint_as_float(b2v << 16);
        acc[5] += __uint_as_float(a2 & 0xffff0000u) + __uint_as_float(b2v & 0xffff0000u);
        acc[6] += __uint_as_float(a3 << 16) + __uint_as_float(b3v << 16);
        acc[7] += __uint_as_float(a3 & 0xffff0000u) + __uint_as_float(b3v & 0xffff0000u);
    }
#pragma unroll
    for (int j = 0; j < 8; j++) {
        acc[j] += __shfl_xor(acc[j], 16);
        acc[j] += __shfl_xor(acc[j], 32);
    }
    if (lane < 16) {
        unsigned w0 = (unsigned)f2bf(acc[0]) | ((unsigned)f2bf(acc[1]) << 16);
        unsigned w1 = (unsigned)f2bf(acc[2]) | ((unsigned)f2bf(acc[3]) << 16);
        unsigned w2 = (unsigned)f2bf(acc[4]) | ((unsigned)f2bf(acc[5]) << 16);
        unsigned w3 = (unsigned)f2bf(acc[6]) | ((unsigned)f2bf(acc[7]) << 16);
        uint4 o = {w0, w1, w2, w3};
        ((uint4*)(aggb + (size_t)wid * HID))[lane] = o;
    }
}

// ------- MFMA GEMM layer 1: h1 = elu([agg1,x] @ Wb1^T + b1) -------
// Weights in LDS (32 KB, XOR-chunk swizzle => conflict-free ds_read_b128),
// A-fragments prefetched to registers (8 independent 16B loads in flight).
__global__ __launch_bounds__(256) void g1_kernel(
    const ushort_t* __restrict__ aggb, const ushort_t* __restrict__ xb,
    const ushort_t* __restrict__ Wb1, const float* __restrict__ b1,
    ushort_t* __restrict__ h1b) {
    __shared__ short8 wl8[2048];                 // 32 KB
    ushort_t* wl = (ushort_t*)wl8;
    // stage: chunk q (16B) of row n=q>>4, c=q&15 -> position c ^ (n&7)
#pragma unroll
    for (int it = 0; it < 8; it++) {
        int q = it * 256 + threadIdx.x;
        int n = q >> 4, c = q & 15;
        short8 v = ((const short8*)Wb1)[q];
        *(short8*)(wl + n * HID + ((c ^ (n & 7)) << 3)) = v;
    }
    __syncthreads();

    int wave = threadIdx.x >> 6;
    int lane = threadIdx.x & 63;
    int nb = blockIdx.x * 128 + wave * 32;
    if (nb >= N_NODES) return;   // after the only barrier
    int half = lane >> 5, col = lane & 31;
    int nA = nb + col;
    if (nA >= N_NODES) nA = N_NODES - 1;

    short8 areg[8];
#pragma unroll
    for (int s = 0; s < 4; s++)
        areg[s] = *(const short8*)(aggb + (size_t)nA * FIN + s * 16 + half * 8);
#pragma unroll
    for (int s = 4; s < 8; s++)
        areg[s] = *(const short8*)(xb + (size_t)nA * FIN + (s - 4) * 16 + half * 8);

    fx16 acc[4];
#pragma unroll
    for (int jt = 0; jt < 4; jt++)
#pragma unroll
        for (int r = 0; r < 16; r++) acc[jt][r] = 0.f;

#pragma unroll
    for (int s = 0; s < 8; s++) {
        int c = 2 * s + half;
#pragma unroll
        for (int jt = 0; jt < 4; jt++) {
            int n = jt * 32 + col;
            short8 bq = *(const short8*)(wl + n * HID + ((c ^ (n & 7)) << 3));
            acc[jt] = __builtin_amdgcn_mfma_f32_32x32x16_bf16(areg[s], bq, acc[jt], 0, 0, 0);
        }
    }
#pragma unroll
    for (int jt = 0; jt < 4; jt++) {
        int j = jt * 32 + col;
        float bias = b1[j];
#pragma unroll
        for (int r = 0; r < 16; r++) {
            int node = nb + (r & 3) + 8 * (r >> 2) + 4 * half;
            if (node < N_NODES) {
                float v = acc[jt][r] + bias;
                v = v > 0.f ? v : __expf(v) - 1.f;
                h1b[(size_t)node * HID + j] = f2bf(v);
            }
        }
    }
}

// ------- MFMA GEMM layer 2 + fused MLP head -------
// Phase 1: t2 = [agg2,h1] @ Wb2^T + b2 (weights in 64 KB LDS, swizzled).
// Phase 2: LDS tile [j][node_local] bf16 (stride 132), node_local includes wave*32.
//          Then out = fc2(relu(fc1(t2))) with 2 threads/node (j-halves), s_load Wfc1.
__global__ __launch_bounds__(256) void g2h_kernel(
    const ushort_t* __restrict__ agg2b, const ushort_t* __restrict__ h1b,
    const ushort_t* __restrict__ Wb2, const float* __restrict__ b2,
    const float* __restrict__ Wfc1, const float* __restrict__ bfc1,
    const float* __restrict__ Wfc2, const float* __restrict__ bfc2,
    float* __restrict__ out) {
    __shared__ short8 smem8[4096];               // 64 KB, reused across phases
    ushort_t* wl = (ushort_t*)smem8;
    // stage Wb2: 4096 chunks, swizzle c -> c ^ (n&7)
#pragma unroll
    for (int it = 0; it < 16; it++) {
        int q = it * 256 + threadIdx.x;
        int n = q >> 5, c = q & 31;
        short8 v = ((const short8*)Wb2)[q];
        *(short8*)(wl + n * 256 + ((c ^ (n & 7)) << 3)) = v;
    }
    __syncthreads();

    int wave = threadIdx.x >> 6;
    int lane = threadIdx.x & 63;
    int half = lane >> 5, col = lane & 31;
    int nb = blockIdx.x * 128 + wave * 32;       // tail waves keep running (barriers!)
    int nA = nb + col;
    if (nA >= N_NODES) nA = N_NODES - 1;

    short8 areg[16];
#pragma unroll
    for (int s = 0; s < 8; s++)
        areg[s] = *(const short8*)(agg2b + (size_t)nA * HID + s * 16 + half * 8);
#pragma unroll
    for (int s = 8; s < 16; s++)
        areg[s] = *(const short8*)(h1b + (size_t)nA * HID + (s - 8) * 16 + half * 8);

    fx16 acc[4];
#pragma unroll
    for (int jt = 0; jt < 4; jt++)
#pragma unroll
        for (int r = 0; r < 16; r++) acc[jt][r] = 0.f;

#pragma unroll
    for (int s = 0; s < 16; s++) {
        int c = 2 * s + half;
#pragma unroll
        for (int jt = 0; jt < 4; jt++) {
            int n = jt * 32 + col;
            short8 bq = *(const short8*)(wl + n * 256 + ((c ^ (n & 7)) << 3));
            acc[jt] = __builtin_amdgcn_mfma_f32_32x32x16_bf16(areg[s], bq, acc[jt], 0, 0, 0);
        }
    }
    __syncthreads();   // all waves done reading weights; LDS now reused for t2 tile

    // tile [j][node_local], bf16, stride 132 (2-way bank aliasing only = free)
    ushort_t* tl = (ushort_t*)smem8;
#pragma unroll
    for (int jt = 0; jt < 4; jt++) {
        int j = jt * 32 + col;
        float bias = b2[j];
#pragma unroll
        for (int rc = 0; rc < 4; rc++) {
            int n0 = wave * 32 + rc * 8 + 4 * half;  // local node = wave offset + C/D row
            us4 pack = {f2bf(acc[jt][rc * 4 + 0] + bias),
                        f2bf(acc[jt][rc * 4 + 1] + bias),
                        f2bf(acc[jt][rc * 4 + 2] + bias),
                        f2bf(acc[jt][rc * 4 + 3] + bias)};
            *(us4*)(tl + j * 132 + n0) = pack;
        }
    }
    __syncthreads();

    // head: thread t -> node (t&127), j-half (t>>7) [wave-uniform -> s_load Wfc1]
    int t = threadIdx.x;
    int n = t & 127;
    int jh = __builtin_amdgcn_readfirstlane(t >> 7);
    int j0 = jh * 64;
    float g[20];
#pragma unroll
    for (int m = 0; m < 20; m++) g[m] = 0.f;
    for (int jj = 0; jj < 64; jj++) {
        int j = j0 + jj;
        float tv = bf2f(tl[j * 132 + n]);
#pragma unroll
        for (int m = 0; m < 20; m++) g[m] += tv * Wfc1[m * HID + j];
    }
    float* gp = (float*)((char*)smem8 + 36864);  // partials, after tile (33792 B)
    if (t >= 128) {
#pragma unroll
        for (int m = 0; m < 20; m++) gp[(t - 128) * 20 + m] = g[m];
    }
    __syncthreads();
    if (t < 128) {
        int ng = blockIdx.x * 128 + n;
        if (ng < N_NODES) {
            float o = bfc2[0];
#pragma unroll
            for (int m = 0; m < 20; m++) {
                float gm = g[m] + gp[t * 20 + m] + bfc1[m];
                o += (gm > 0.f ? gm : 0.f) * Wfc2[m];
            }
            out[ng] = o;
        }
    }
}

// ---------------- launch ----------------
extern "C" void kernel_launch(void* const* d_in, const int* in_sizes, int n_in,
                              void* d_out, int out_size, void* d_ws, size_t ws_size,
                              hipStream_t stream) {
    const float* x = (const float*)d_in[0];
    const int* ei = (const int*)d_in[1];
    const float* W1rel = (const float*)d_in[2];
    const float* b1 = (const float*)d_in[3];
    const float* W1root = (const float*)d_in[4];
    const float* W2rel = (const float*)d_in[5];
    const float* b2 = (const float*)d_in[6];
    const float* W2root = (const float*)d_in[7];
    const float* Wfc1 = (const float*)d_in[8];
    const float* bfc1 = (const float*)d_in[9];
    const float* Wfc2 = (const float*)d_in[10];
    const float* bfc2 = (const float*)d_in[11];
    float* out = (float*)d_out;

    char* ws = (char*)d_ws;
    size_t o = 0;
    int* deg = (int*)(ws + o);       o += (size_t)N_NODES * 4;
    int* off = (int*)(ws + o);       o += (size_t)(N_NODES + 1) * 4 + 12;
    int* bsums = (int*)(ws + o);     o += 4096;
    int* flag = (int*)(ws + o);      o += 16;
    int* rank = (int*)(ws + o);      o += (size_t)N_EDGES * 4;          // 3.2 MB
    int* srcs = (int*)(ws + o);      o += (size_t)N_EDGES * 4;          // 3.2 MB
    ushort_t* xb = (ushort_t*)(ws + o);    o += (size_t)N_NODES * FIN * 2;  // 12.8 MB
    ushort_t* agg1b = (ushort_t*)(ws + o); o += (size_t)N_NODES * FIN * 2;  // 12.8 MB
    ushort_t* h1b = (ushort_t*)(ws + o);   o += (size_t)N_NODES * HID * 2;  // 25.6 MB
    ushort_t* agg2b = (ushort_t*)(ws + o); o += (size_t)N_NODES * HID * 2;  // 25.6 MB
    ushort_t* Wb1 = (ushort_t*)(ws + o);   o += (size_t)HID * HID * 2;      // 32 KB
    ushort_t* Wb2 = (ushort_t*)(ws + o);   o += (size_t)HID * 2 * HID * 2;  // 64 KB

    const int GW = (N_NODES + 127) / 128; // 782 blocks: 4 waves x 32 nodes

    zero_int_kernel<<<NB1, 256, 0, stream>>>(deg, N_NODES);
    zero_int_kernel<<<1, 256, 0, stream>>>(flag, 1);
    detect_kernel<<<32, 256, 0, stream>>>(ei, flag);
    hist_kernel<<<(N_EDGES + 255) / 256, 256, 0, stream>>>(ei, flag, deg, rank);
    scan1_kernel<<<NB1, 256, 0, stream>>>(deg, off, bsums);
    scan2_kernel<<<1, 512, 0, stream>>>(bsums);
    scan3_kernel<<<NB1, 256, 0, stream>>>(off, bsums);
    scatter_kernel<<<(N_EDGES + 255) / 256, 256, 0, stream>>>(ei, flag, off, rank, srcs);
    xcvt_kernel<<<(N_NODES * FIN / 4 + 255) / 256, 256, 0, stream>>>(x, xb);
    wcvt_kernel<<<(HID * 2 * HID + 255) / 256, 256, 0, stream>>>(W1rel, W1root, W2rel, W2root, Wb1, Wb2);
    agg1_kernel<<<N_NODES / 4, 256, 0, stream>>>(xb, off, srcs, agg1b);
    g1_kernel<<<GW, 256, 0, stream>>>(agg1b, xb, Wb1, b1, h1b);
    agg2_kernel<<<N_NODES / 4, 256, 0, stream>>>(h1b, off, srcs, agg2b);
    g2h_kernel<<<GW, 256, 0, stream>>>(agg2b, h1b, Wb2, b2, Wfc1, bfc1, Wfc2, bfc2, out);
}

// Round 8
// 281.021 us; speedup vs baseline: 5.9441x; 1.0223x over previous
//
#include <hip/hip_runtime.h>

#define N_NODES 100000
#define N_EDGES 800000
#define FIN 64
#define HID 128
#define NB1 391   // ceil(N_NODES/256)

typedef unsigned short ushort_t;
typedef __attribute__((ext_vector_type(8))) short short8;   // 8 bf16 = 4 VGPRs (MFMA A/B frag)
typedef __attribute__((ext_vector_type(16))) float fx16;    // 32x32 MFMA C/D frag
typedef __attribute__((ext_vector_type(4))) unsigned short us4;

__device__ inline ushort_t f2bf(float f) {   // RNE fp32 -> bf16
    unsigned u = __float_as_uint(f);
    u += 0x7fffu + ((u >> 16) & 1u);
    return (ushort_t)(u >> 16);
}
__device__ inline float bf2f(ushort_t h) { return __uint_as_float(((unsigned)h) << 16); }

// ---------------- utility ----------------
__global__ void zero_int_kernel(int* __restrict__ p, int n) {
    int i = blockIdx.x * 256 + threadIdx.x;
    if (i < n) p[i] = 0;
}

// int32 vs int64 edge_index layout probe (int64 little-endian => odd words all 0)
__global__ void detect_kernel(const int* __restrict__ w, int* __restrict__ flag) {
    int i = blockIdx.x * 256 + threadIdx.x;
    if (i < 8192) {
        if (w[2 * i + 1] != 0) atomicOr(flag, 1);
    }
}

// ---------------- CSR build ----------------
__global__ void hist_kernel(const int* __restrict__ w, const int* __restrict__ flag,
                            int* __restrict__ deg, int* __restrict__ rank) {
    int e = blockIdx.x * 256 + threadIdx.x;
    if (e >= N_EDGES) return;
    int is32 = *flag;
    int d = is32 ? w[N_EDGES + e] : w[2 * (N_EDGES + e)];
    rank[e] = atomicAdd(&deg[d], 1);
}

__global__ void scan1_kernel(const int* __restrict__ deg, int* __restrict__ off,
                             int* __restrict__ bsums) {
    __shared__ int s[256];
    int t = threadIdx.x;
    int i = blockIdx.x * 256 + t;
    int v = (i < N_NODES) ? deg[i] : 0;
    s[t] = v;
    __syncthreads();
    for (int d = 1; d < 256; d <<= 1) {
        int w = (t >= d) ? s[t - d] : 0;
        __syncthreads();
        s[t] += w;
        __syncthreads();
    }
    if (i < N_NODES) off[i] = s[t] - v;
    if (t == 255) bsums[blockIdx.x] = s[255];
}

__global__ void scan2_kernel(int* __restrict__ bsums) {
    __shared__ int s[512];
    int t = threadIdx.x;
    int v = (t < NB1) ? bsums[t] : 0;
    s[t] = v;
    __syncthreads();
    for (int d = 1; d < 512; d <<= 1) {
        int w = (t >= d) ? s[t - d] : 0;
        __syncthreads();
        s[t] += w;
        __syncthreads();
    }
    if (t < NB1) bsums[t] = s[t] - v;
}

__global__ void scan3_kernel(int* __restrict__ off, const int* __restrict__ bsums) {
    int i = blockIdx.x * 256 + threadIdx.x;
    if (i < N_NODES) off[i] = off[i] + bsums[blockIdx.x];
    if (i == 0) off[N_NODES] = N_EDGES;
}

__global__ void scatter_kernel(const int* __restrict__ w, const int* __restrict__ flag,
                               const int* __restrict__ off, const int* __restrict__ rank,
                               int* __restrict__ srcs) {
    int e = blockIdx.x * 256 + threadIdx.x;
    if (e >= N_EDGES) return;
    int is32 = *flag;
    int s = is32 ? w[e] : w[2 * e];
    int d = is32 ? w[N_EDGES + e] : w[2 * (N_EDGES + e)];
    srcs[off[d] + rank[e]] = s;
}

// ---------------- dtype conversion ----------------
__global__ void xcvt_kernel(const float* __restrict__ x, ushort_t* __restrict__ xb) {
    int i = blockIdx.x * 256 + threadIdx.x; // quad id
    if (i >= N_NODES * FIN / 4) return;
    float4 v = ((const float4*)x)[i];
    us4 o = {f2bf(v.x), f2bf(v.y), f2bf(v.z), f2bf(v.w)};
    ((us4*)xb)[i] = o;
}

// Wb1[n][k], k<64 -> W1rel, else W1root. Wb2[n][k], k<128 -> W2rel, else W2root.
__global__ void wcvt_kernel(const float* __restrict__ W1rel, const float* __restrict__ W1root,
                            const float* __restrict__ W2rel, const float* __restrict__ W2root,
                            ushort_t* __restrict__ Wb1, ushort_t* __restrict__ Wb2) {
    int i = blockIdx.x * 256 + threadIdx.x;
    if (i < HID * HID) {
        int n = i >> 7, k = i & 127;
        float v = (k < FIN) ? W1rel[n * FIN + k] : W1root[n * FIN + (k - FIN)];
        Wb1[i] = f2bf(v);
    }
    if (i < HID * 2 * HID) {
        int n = i >> 8, k = i & 255;
        float v = (k < HID) ? W2rel[n * HID + k] : W2root[n * HID + (k - HID)];
        Wb2[i] = f2bf(v);
    }
}

// ------- aggregation: wave per node, slot-parallel vectorized gather -------
__global__ void agg1_kernel(const ushort_t* __restrict__ xb, const int* __restrict__ off,
                            const int* __restrict__ srcs, ushort_t* __restrict__ aggb) {
    int wid = (blockIdx.x * 256 + threadIdx.x) >> 6; // node
    int lane = threadIdx.x & 63;
    if (wid >= N_NODES) return;
    int b = __builtin_amdgcn_readfirstlane(off[wid]);
    int e = __builtin_amdgcn_readfirstlane(off[wid + 1]);
    int g = lane >> 3;   // edge slot 0..7
    int c = lane & 7;    // 16B chunk of the 128B row
    float acc[8];
#pragma unroll
    for (int j = 0; j < 8; j++) acc[j] = 0.f;
    const uint4* rows = (const uint4*)xb;    // 8 chunks per row
    for (int p = b; p < e; p += 8) {
        int i0 = p + g;
        bool q0 = i0 < e;
        int s0 = srcs[q0 ? i0 : e - 1];      // clamped: always in-bounds, real data
        uint4 A = rows[(size_t)s0 * 8 + c];
        unsigned a0 = q0 ? A.x : 0u, a1 = q0 ? A.y : 0u;
        unsigned a2 = q0 ? A.z : 0u, a3 = q0 ? A.w : 0u;
        acc[0] += __uint_as_float(a0 << 16);
        acc[1] += __uint_as_float(a0 & 0xffff0000u);
        acc[2] += __uint_as_float(a1 << 16);
        acc[3] += __uint_as_float(a1 & 0xffff0000u);
        acc[4] += __uint_as_float(a2 << 16);
        acc[5] += __uint_as_float(a2 & 0xffff0000u);
        acc[6] += __uint_as_float(a3 << 16);
        acc[7] += __uint_as_float(a3 & 0xffff0000u);
    }
#pragma unroll
    for (int j = 0; j < 8; j++) {
        acc[j] += __shfl_xor(acc[j], 8);
        acc[j] += __shfl_xor(acc[j], 16);
        acc[j] += __shfl_xor(acc[j], 32);
    }
    if (lane < 8) {
        unsigned w0 = (unsigned)f2bf(acc[0]) | ((unsigned)f2bf(acc[1]) << 16);
        unsigned w1 = (unsigned)f2bf(acc[2]) | ((unsigned)f2bf(acc[3]) << 16);
        unsigned w2 = (unsigned)f2bf(acc[4]) | ((unsigned)f2bf(acc[5]) << 16);
        unsigned w3 = (unsigned)f2bf(acc[6]) | ((unsigned)f2bf(acc[7]) << 16);
        uint4 o = {w0, w1, w2, w3};
        ((uint4*)(aggb + (size_t)wid * FIN))[lane] = o;
    }
}

__global__ void agg2_kernel(const ushort_t* __restrict__ h1b, const int* __restrict__ off,
                            const int* __restrict__ srcs, ushort_t* __restrict__ aggb) {
    int wid = (blockIdx.x * 256 + threadIdx.x) >> 6; // node
    int lane = threadIdx.x & 63;
    if (wid >= N_NODES) return;
    int b = __builtin_amdgcn_readfirstlane(off[wid]);
    int e = __builtin_amdgcn_readfirstlane(off[wid + 1]);
    int g = lane >> 4;   // edge slot 0..3
    int c = lane & 15;   // 16B chunk of the 256B row
    float acc[8];
#pragma unroll
    for (int j = 0; j < 8; j++) acc[j] = 0.f;
    const uint4* rows = (const uint4*)h1b;   // 16 chunks per row
    for (int p = b; p < e; p += 8) {
        int i0 = p + g, i1 = p + 4 + g;
        bool q0 = i0 < e, q1 = i1 < e;
        int s0 = srcs[q0 ? i0 : e - 1];
        int s1 = srcs[q1 ? i1 : e - 1];
        uint4 A = rows[(size_t)s0 * 16 + c];
        uint4 B = rows[(size_t)s1 * 16 + c];
        unsigned a0 = q0 ? A.x : 0u, a1 = q0 ? A.y : 0u;
        unsigned a2 = q0 ? A.z : 0u, a3 = q0 ? A.w : 0u;
        unsigned b0 = q1 ? B.x : 0u, b1v = q1 ? B.y : 0u;
        unsigned b2v = q1 ? B.z : 0u, b3v = q1 ? B.w : 0u;
        acc[0] += __uint_as_float(a0 << 16) + __uint_as_float(b0 << 16);
        acc[1] += __uint_as_float(a0 & 0xffff0000u) + __uint_as_float(b0 & 0xffff0000u);
        acc[2] += __uint_as_float(a1 << 16) + __uint_as_float(b1v << 16);
        acc[3] += __uint_as_float(a1 & 0xffff0000u) + __uint_as_float(b1v & 0xffff0000u);
        acc[4] += __uint_as_float(a2 << 16) + __uint_as_float(b2v << 16);
        acc[5] += __uint_as_float(a2 & 0xffff0000u) + __uint_as_float(b2v & 0xffff0000u);
        acc[6] += __uint_as_float(a3 << 16) + __uint_as_float(b3v << 16);
        acc[7] += __uint_as_float(a3 & 0xffff0000u) + __uint_as_float(b3v & 0xffff0000u);
    }
#pragma unroll
    for (int j = 0; j < 8; j++) {
        acc[j] += __shfl_xor(acc[j], 16);
        acc[j] += __shfl_xor(acc[j], 32);
    }
    if (lane < 16) {
        unsigned w0 = (unsigned)f2bf(acc[0]) | ((unsigned)f2bf(acc[1]) << 16);
        unsigned w1 = (unsigned)f2bf(acc[2]) | ((unsigned)f2bf(acc[3]) << 16);
        unsigned w2 = (unsigned)f2bf(acc[4]) | ((unsigned)f2bf(acc[5]) << 16);
        unsigned w3 = (unsigned)f2bf(acc[6]) | ((unsigned)f2bf(acc[7]) << 16);
        uint4 o = {w0, w1, w2, w3};
        ((uint4*)(aggb + (size_t)wid * HID))[lane] = o;
    }
}

// ------- MFMA GEMM layer 1: h1 = elu([agg1,x] @ Wb1^T + b1) -------
__global__ __launch_bounds__(256) void g1_kernel(
    const ushort_t* __restrict__ aggb, const ushort_t* __restrict__ xb,
    const ushort_t* __restrict__ Wb1, const float* __restrict__ b1,
    ushort_t* __restrict__ h1b) {
    __shared__ short8 wl8[2048];                 // 32 KB
    ushort_t* wl = (ushort_t*)wl8;
#pragma unroll
    for (int it = 0; it < 8; it++) {
        int q = it * 256 + threadIdx.x;
        int n = q >> 4, c = q & 15;
        short8 v = ((const short8*)Wb1)[q];
        *(short8*)(wl + n * HID + ((c ^ (n & 7)) << 3)) = v;
    }
    __syncthreads();

    int wave = threadIdx.x >> 6;
    int lane = threadIdx.x & 63;
    int nb = blockIdx.x * 128 + wave * 32;
    if (nb >= N_NODES) return;   // after the only barrier
    int half = lane >> 5, col = lane & 31;
    int nA = nb + col;
    if (nA >= N_NODES) nA = N_NODES - 1;

    short8 areg[8];
#pragma unroll
    for (int s = 0; s < 4; s++)
        areg[s] = *(const short8*)(aggb + (size_t)nA * FIN + s * 16 + half * 8);
#pragma unroll
    for (int s = 4; s < 8; s++)
        areg[s] = *(const short8*)(xb + (size_t)nA * FIN + (s - 4) * 16 + half * 8);

    fx16 acc[4];
#pragma unroll
    for (int jt = 0; jt < 4; jt++)
#pragma unroll
        for (int r = 0; r < 16; r++) acc[jt][r] = 0.f;

#pragma unroll
    for (int s = 0; s < 8; s++) {
        int c = 2 * s + half;
#pragma unroll
        for (int jt = 0; jt < 4; jt++) {
            int n = jt * 32 + col;
            short8 bq = *(const short8*)(wl + n * HID + ((c ^ (n & 7)) << 3));
            acc[jt] = __builtin_amdgcn_mfma_f32_32x32x16_bf16(areg[s], bq, acc[jt], 0, 0, 0);
        }
    }
#pragma unroll
    for (int jt = 0; jt < 4; jt++) {
        int j = jt * 32 + col;
        float bias = b1[j];
#pragma unroll
        for (int r = 0; r < 16; r++) {
            int node = nb + (r & 3) + 8 * (r >> 2) + 4 * half;
            if (node < N_NODES) {
                float v = acc[jt][r] + bias;
                v = v > 0.f ? v : __expf(v) - 1.f;
                h1b[(size_t)node * HID + j] = f2bf(v);
            }
        }
    }
}

// ------- MFMA GEMM layer 2 + MFMA MLP head -------
// LDS (43008 B, 3 blocks/CU):
//   [0..32768)      Wb2 K-half staging (32 KB, two passes), later t2 tile
//   [0..34816)      t2 tile [node][feature], stride 136 ushorts (16B-aligned rows)
//   [34816..43008)  Wfc1 padded 32x128 bf16, XOR-swizzled (disjoint from Wb2 region)
// Head: fc1 as 8 MFMAs on the tile, relu*Wfc2 per lane, 5-round shfl_xor butterfly.
__global__ __launch_bounds__(256) void g2h_kernel(
    const ushort_t* __restrict__ agg2b, const ushort_t* __restrict__ h1b,
    const ushort_t* __restrict__ Wb2, const float* __restrict__ b2,
    const float* __restrict__ Wfc1, const float* __restrict__ bfc1,
    const float* __restrict__ Wfc2, const float* __restrict__ bfc2,
    float* __restrict__ out) {
    __shared__ ushort_t smem[21504];             // 43008 B
    ushort_t* wl = smem;                         // 16384 ushorts (32 KB)
    ushort_t* wf = smem + 17408;                 // 4096 ushorts (8 KB)

    // stage Wfc1b once (region never touched by Wb2/tile)
#pragma unroll
    for (int it = 0; it < 16; it++) {
        int idx = it * 256 + threadIdx.x;        // 0..4095
        int m = idx >> 7, k = idx & 127;
        float v = (m < 20) ? Wfc1[m * HID + k] : 0.f;
        wf[m * 128 + (((k >> 3) ^ (m & 7)) << 3) + (k & 7)] = f2bf(v);
    }
    // stage Wb2 K-half 0 (cols 0..127)
#pragma unroll
    for (int it = 0; it < 8; it++) {
        int q = it * 256 + threadIdx.x;          // 0..2047
        int n = q >> 4, c = q & 15;
        short8 v = *(const short8*)(Wb2 + (size_t)n * 256 + c * 8);
        *(short8*)(wl + n * 128 + ((c ^ (n & 7)) << 3)) = v;
    }

    int wave = threadIdx.x >> 6;
    int lane = threadIdx.x & 63;
    int half = lane >> 5, col = lane & 31;
    int nb = blockIdx.x * 128 + wave * 32;       // tail waves keep running (barriers!)
    int nA = nb + col;
    if (nA >= N_NODES) nA = N_NODES - 1;

    short8 areg[16];
#pragma unroll
    for (int s = 0; s < 8; s++)
        areg[s] = *(const short8*)(agg2b + (size_t)nA * HID + s * 16 + half * 8);
#pragma unroll
    for (int s = 8; s < 16; s++)
        areg[s] = *(const short8*)(h1b + (size_t)nA * HID + (s - 8) * 16 + half * 8);

    fx16 acc[4];
#pragma unroll
    for (int jt = 0; jt < 4; jt++)
#pragma unroll
        for (int r = 0; r < 16; r++) acc[jt][r] = 0.f;

    __syncthreads();
#pragma unroll
    for (int s = 0; s < 8; s++) {                // K 0..127 (agg2 part)
        int c = 2 * s + half;
#pragma unroll
        for (int jt = 0; jt < 4; jt++) {
            int n = jt * 32 + col;
            short8 bq = *(const short8*)(wl + n * 128 + ((c ^ (n & 7)) << 3));
            acc[jt] = __builtin_amdgcn_mfma_f32_32x32x16_bf16(areg[s], bq, acc[jt], 0, 0, 0);
        }
    }
    __syncthreads();
    // stage Wb2 K-half 1 (cols 128..255)
#pragma unroll
    for (int it = 0; it < 8; it++) {
        int q = it * 256 + threadIdx.x;
        int n = q >> 4, c = q & 15;
        short8 v = *(const short8*)(Wb2 + (size_t)n * 256 + 128 + c * 8);
        *(short8*)(wl + n * 128 + ((c ^ (n & 7)) << 3)) = v;
    }
    __syncthreads();
#pragma unroll
    for (int s = 8; s < 16; s++) {               // K 128..255 (h1 part)
        int c = 2 * (s - 8) + half;
#pragma unroll
        for (int jt = 0; jt < 4; jt++) {
            int n = jt * 32 + col;
            short8 bq = *(const short8*)(wl + n * 128 + ((c ^ (n & 7)) << 3));
            acc[jt] = __builtin_amdgcn_mfma_f32_32x32x16_bf16(areg[s], bq, acc[jt], 0, 0, 0);
        }
    }
    __syncthreads();   // weights dead; reuse [0..34816) as t2 tile

    // t2 tile [node_local][feature], stride 136 ushorts
    ushort_t* tl = smem;
#pragma unroll
    for (int jt = 0; jt < 4; jt++) {
        int j = jt * 32 + col;
        float bias = b2[j];
#pragma unroll
        for (int r = 0; r < 16; r++) {
            int nl = wave * 32 + (r & 3) + 8 * (r >> 2) + 4 * half;
            tl[nl * 136 + j] = f2bf(acc[jt][r] + bias);
        }
    }
    __syncthreads();

    // fc1 as MFMA: A = t2 tile rows (node m = wave*32+col), B = Wfc1b (row col)
    short8 af[8];
#pragma unroll
    for (int s = 0; s < 8; s++)
        af[s] = *(const short8*)(tl + (wave * 32 + col) * 136 + s * 16 + half * 8);
    fx16 fa;
#pragma unroll
    for (int r = 0; r < 16; r++) fa[r] = 0.f;
#pragma unroll
    for (int s = 0; s < 8; s++) {
        int c = 2 * s + half;
        short8 bw = *(const short8*)(wf + col * 128 + ((c ^ (col & 7)) << 3));
        fa = __builtin_amdgcn_mfma_f32_32x32x16_bf16(af[s], bw, fa, 0, 0, 0);
    }
    // epilogue: relu(+bfc1) * Wfc2, butterfly-sum over the 32 output cols
    float biasv = (col < 20) ? bfc1[col] : 0.f;
    float w2v = (col < 20) ? Wfc2[col] : 0.f;
    float bz = bfc2[0];
    float red[16];
#pragma unroll
    for (int r = 0; r < 16; r++) {
        float v = fa[r] + biasv;
        v = (v > 0.f ? v : 0.f) * w2v;
        v += __shfl_xor(v, 1);
        v += __shfl_xor(v, 2);
        v += __shfl_xor(v, 4);
        v += __shfl_xor(v, 8);
        v += __shfl_xor(v, 16);
        red[r] = v;
    }
    if (col == 0) {
#pragma unroll
        for (int r = 0; r < 16; r++) {
            int nl = wave * 32 + (r & 3) + 8 * (r >> 2) + 4 * half;
            int ng = blockIdx.x * 128 + nl;
            if (ng < N_NODES) out[ng] = red[r] + bz;
        }
    }
}

// ---------------- launch ----------------
extern "C" void kernel_launch(void* const* d_in, const int* in_sizes, int n_in,
                              void* d_out, int out_size, void* d_ws, size_t ws_size,
                              hipStream_t stream) {
    const float* x = (const float*)d_in[0];
    const int* ei = (const int*)d_in[1];
    const float* W1rel = (const float*)d_in[2];
    const float* b1 = (const float*)d_in[3];
    const float* W1root = (const float*)d_in[4];
    const float* W2rel = (const float*)d_in[5];
    const float* b2 = (const float*)d_in[6];
    const float* W2root = (const float*)d_in[7];
    const float* Wfc1 = (const float*)d_in[8];
    const float* bfc1 = (const float*)d_in[9];
    const float* Wfc2 = (const float*)d_in[10];
    const float* bfc2 = (const float*)d_in[11];
    float* out = (float*)d_out;

    char* ws = (char*)d_ws;
    size_t o = 0;
    int* deg = (int*)(ws + o);       o += (size_t)N_NODES * 4;
    int* off = (int*)(ws + o);       o += (size_t)(N_NODES + 1) * 4 + 12;
    int* bsums = (int*)(ws + o);     o += 4096;
    int* flag = (int*)(ws + o);      o += 16;
    int* rank = (int*)(ws + o);      o += (size_t)N_EDGES * 4;          // 3.2 MB
    int* srcs = (int*)(ws + o);      o += (size_t)N_EDGES * 4;          // 3.2 MB
    ushort_t* xb = (ushort_t*)(ws + o);    o += (size_t)N_NODES * FIN * 2;  // 12.8 MB
    ushort_t* agg1b = (ushort_t*)(ws + o); o += (size_t)N_NODES * FIN * 2;  // 12.8 MB
    ushort_t* h1b = (ushort_t*)(ws + o);   o += (size_t)N_NODES * HID * 2;  // 25.6 MB
    ushort_t* agg2b = (ushort_t*)(ws + o); o += (size_t)N_NODES * HID * 2;  // 25.6 MB
    ushort_t* Wb1 = (ushort_t*)(ws + o);   o += (size_t)HID * HID * 2;      // 32 KB
    ushort_t* Wb2 = (ushort_t*)(ws + o);   o += (size_t)HID * 2 * HID * 2;  // 64 KB

    const int GW = (N_NODES + 127) / 128; // 782 blocks: 4 waves x 32 nodes

    zero_int_kernel<<<NB1, 256, 0, stream>>>(deg, N_NODES);
    zero_int_kernel<<<1, 256, 0, stream>>>(flag, 1);
    detect_kernel<<<32, 256, 0, stream>>>(ei, flag);
    hist_kernel<<<(N_EDGES + 255) / 256, 256, 0, stream>>>(ei, flag, deg, rank);
    scan1_kernel<<<NB1, 256, 0, stream>>>(deg, off, bsums);
    scan2_kernel<<<1, 512, 0, stream>>>(bsums);
    scan3_kernel<<<NB1, 256, 0, stream>>>(off, bsums);
    scatter_kernel<<<(N_EDGES + 255) / 256, 256, 0, stream>>>(ei, flag, off, rank, srcs);
    xcvt_kernel<<<(N_NODES * FIN / 4 + 255) / 256, 256, 0, stream>>>(x, xb);
    wcvt_kernel<<<(HID * 2 * HID + 255) / 256, 256, 0, stream>>>(W1rel, W1root, W2rel, W2root, Wb1, Wb2);
    agg1_kernel<<<N_NODES / 4, 256, 0, stream>>>(xb, off, srcs, agg1b);
    g1_kernel<<<GW, 256, 0, stream>>>(agg1b, xb, Wb1, b1, h1b);
    agg2_kernel<<<N_NODES / 4, 256, 0, stream>>>(h1b, off, srcs, agg2b);
    g2h_kernel<<<GW, 256, 0, stream>>>(agg2b, h1b, Wb2, b2, Wfc1, bfc1, Wfc2, bfc2, out);
}